// Round 1
// baseline (1417.623 us; speedup 1.0000x reference)
//
#include <hip/hip_runtime.h>

// RegionSeparatedAttention on MI355X — round 0: correct fp32 scaffold.
//
// Shapes: x [2,64,128,128], grid 2x2 -> 8 (b,region) pairs, each region
// C=64 channels x N=4096 pixels.  S = q^T k / 8 (N x N per region),
// P = softmax_rows(S), out = A*P + B*P^T, then 1x1 conv Wo.
//
// Pipeline (all on `stream`):
//   k_conv_in : x -> Q,K,A,Bt in regionized [br][c][n] layout (ws)
//   k_stats   : per-row online softmax stats M[br][n], L[br][n]
//   k_out2    : OutR  = Bt * P^T   (flash-style, S rows recomputed)
//   k_out1    : OutR += A * P      (S columns via recompute)
//   k_conv_out: OutR -> conv Wo -> d_out [2,64,128,128]

constexpr size_t TEN   = 2097152;          // 8 * 64 * 4096 floats per tensor
constexpr size_t QOFF  = 0;
constexpr size_t KOFF  = TEN;
constexpr size_t AOFF  = 2 * TEN;
constexpr size_t BOFF2 = 3 * TEN;
constexpr size_t MOFF  = 4 * TEN;          // [8][4096]
constexpr size_t LOFF  = 4 * TEN + 32768;  // [8][4096]
constexpr size_t OOFF  = 4 * TEN + 65536;  // [8][64][4096]
constexpr int BRS = 64 * 4096;             // per-region stride (floats)

__device__ __forceinline__ void load4(float* dst, const float4 v) {
    dst[0] = v.x; dst[1] = v.y; dst[2] = v.z; dst[3] = v.w;
}

// ---------------------------------------------------------------- k_conv_in
__global__ __launch_bounds__(256) void k_conv_in(
    const float* __restrict__ x,
    const float* __restrict__ Wq, const float* __restrict__ bq,
    const float* __restrict__ Wk, const float* __restrict__ bk,
    const float* __restrict__ Wa, const float* __restrict__ ba,
    const float* __restrict__ Wb, const float* __restrict__ bb,
    float* __restrict__ ws)
{
    const int tid  = threadIdx.x;
    const int blk  = blockIdx.x;
    const int wseg = blk & 1;          // gj
    const int h    = (blk >> 1) & 127;
    const int b    = blk >> 8;

    __shared__ float xs[64][68];       // [c][w] for this 64-pixel row segment

    const float* xp = x + ((size_t)b * 64 * 16384) + (size_t)h * 128 + wseg * 64;
    #pragma unroll
    for (int r = 0; r < 4; ++r) {
        int idx = r * 256 + tid;
        int c   = idx >> 4;
        int w4  = (idx & 15) << 2;
        *(float4*)&xs[c][w4] = *(const float4*)(xp + (size_t)c * 16384 + w4);
    }
    __syncthreads();

    const int mat = tid >> 6;          // 0..3 : q,k,a,b
    const int oc  = tid & 63;
    const float* Wsel = (mat == 0) ? Wq : (mat == 1) ? Wk : (mat == 2) ? Wa : Wb;
    const float* bsel = (mat == 0) ? bq : (mat == 1) ? bk : (mat == 2) ? ba : bb;
    float* osel = ws + ((mat == 0) ? QOFF : (mat == 1) ? KOFF : (mat == 2) ? AOFF : BOFF2);

    float acc[64];
    const float bias = bsel[oc];
    #pragma unroll
    for (int w = 0; w < 64; ++w) acc[w] = bias;

    #pragma unroll 8
    for (int c = 0; c < 64; ++c) {
        const float wv = Wsel[oc * 64 + c];
        #pragma unroll
        for (int w = 0; w < 64; ++w) acc[w] = fmaf(wv, xs[c][w], acc[w]);
    }

    const int gi = h >> 6, i = h & 63;
    const int br = b * 4 + gi * 2 + wseg;
    float* op = osel + (size_t)br * BRS + (size_t)oc * 4096 + i * 64;
    #pragma unroll
    for (int w4 = 0; w4 < 16; ++w4)
        *(float4*)(op + w4 * 4) =
            make_float4(acc[w4*4], acc[w4*4+1], acc[w4*4+2], acc[w4*4+3]);
}

// ------------------------------------------------------------------ k_stats
// Per (br, 64-row tile): online softmax row stats over all 4096 columns.
__global__ __launch_bounds__(256) void k_stats(float* __restrict__ ws)
{
    const int tid = threadIdx.x;
    const int nt  = blockIdx.x & 63;
    const int br  = blockIdx.x >> 6;

    const float* Q = ws + QOFF + (size_t)br * BRS;
    const float* K = ws + KOFF + (size_t)br * BRS;

    __shared__ float qs[64][68];   // [c][n_local]
    __shared__ float ks[64][68];   // [c][m_local]

    #pragma unroll
    for (int r = 0; r < 4; ++r) {
        int idx = r * 256 + tid;
        int c   = idx >> 4;
        int n4  = (idx & 15) << 2;
        *(float4*)&qs[c][n4] = *(const float4*)(Q + (size_t)c * 4096 + nt * 64 + n4);
    }

    const int tx = tid & 15, ty = tid >> 4;   // thread tile: n = ty*4.., m = tx*4..

    float mx[4], sm[4];
    #pragma unroll
    for (int i = 0; i < 4; ++i) { mx[i] = -3.0e38f; sm[i] = 0.f; }

    for (int mt = 0; mt < 64; ++mt) {
        __syncthreads();
        #pragma unroll
        for (int r = 0; r < 4; ++r) {
            int idx = r * 256 + tid;
            int c   = idx >> 4;
            int m4  = (idx & 15) << 2;
            *(float4*)&ks[c][m4] = *(const float4*)(K + (size_t)c * 4096 + mt * 64 + m4);
        }
        __syncthreads();

        float s[4][4];
        #pragma unroll
        for (int i = 0; i < 4; ++i)
            #pragma unroll
            for (int k = 0; k < 4; ++k) s[i][k] = 0.f;

        #pragma unroll 8
        for (int c = 0; c < 64; ++c) {
            float qa[4], ka[4];
            load4(qa, *(const float4*)&qs[c][ty * 4]);
            load4(ka, *(const float4*)&ks[c][tx * 4]);
            #pragma unroll
            for (int i = 0; i < 4; ++i)
                #pragma unroll
                for (int k = 0; k < 4; ++k)
                    s[i][k] = fmaf(qa[i], ka[k], s[i][k]);
        }

        #pragma unroll
        for (int i = 0; i < 4; ++i) {
            float t0 = fmaxf(fmaxf(s[i][0], s[i][1]), fmaxf(s[i][2], s[i][3])) * 0.125f;
            float nm = fmaxf(mx[i], t0);
            float add = __expf(s[i][0]*0.125f - nm) + __expf(s[i][1]*0.125f - nm)
                      + __expf(s[i][2]*0.125f - nm) + __expf(s[i][3]*0.125f - nm);
            sm[i] = sm[i] * __expf(mx[i] - nm) + add;
            mx[i] = nm;
        }
    }

    // combine across the 16 tx-threads sharing each row (lanes xor 1,2,4,8)
    #pragma unroll
    for (int off = 1; off < 16; off <<= 1) {
        #pragma unroll
        for (int i = 0; i < 4; ++i) {
            float omx = __shfl_xor(mx[i], off);
            float osm = __shfl_xor(sm[i], off);
            float nm  = fmaxf(mx[i], omx);
            sm[i] = sm[i] * __expf(mx[i] - nm) + osm * __expf(omx - nm);
            mx[i] = nm;
        }
    }
    if (tx == 0) {
        float* Ms = ws + MOFF + (size_t)br * 4096;
        float* Ls = ws + LOFF + (size_t)br * 4096;
        #pragma unroll
        for (int i = 0; i < 4; ++i) {
            Ms[nt * 64 + ty * 4 + i] = mx[i];
            Ls[nt * 64 + ty * 4 + i] = sm[i];
        }
    }
}

// ------------------------------------------------------------------- k_out2
// OutR[c][m] = sum_j P[m][j] * Bt[c][j]   (standard flash direction)
__global__ __launch_bounds__(256) void k_out2(float* __restrict__ ws)
{
    const int tid = threadIdx.x;
    const int mt  = blockIdx.x & 63;
    const int br  = blockIdx.x >> 6;

    const float* Q  = ws + QOFF  + (size_t)br * BRS;
    const float* K  = ws + KOFF  + (size_t)br * BRS;
    const float* Bt = ws + BOFF2 + (size_t)br * BRS;
    const float* Ms = ws + MOFF  + (size_t)br * 4096;
    const float* Ls = ws + LOFF  + (size_t)br * 4096;
    float* OutR     = ws + OOFF  + (size_t)br * BRS;

    __shared__ float qm[64][68];   // q columns at this m-tile (persistent)
    __shared__ float kj[64][68];
    __shared__ float bj[64][68];
    __shared__ float w2[64][68];   // [m_local][j_local]

    #pragma unroll
    for (int r = 0; r < 4; ++r) {
        int idx = r * 256 + tid;
        int c   = idx >> 4;
        int m4  = (idx & 15) << 2;
        *(float4*)&qm[c][m4] = *(const float4*)(Q + (size_t)c * 4096 + mt * 64 + m4);
    }

    const int tx = tid & 15, ty = tid >> 4;

    float Mv[4], Li[4];
    #pragma unroll
    for (int i = 0; i < 4; ++i) {
        Mv[i] = Ms[mt * 64 + ty * 4 + i];
        Li[i] = 1.0f / Ls[mt * 64 + ty * 4 + i];
    }

    float acc[4][4];
    #pragma unroll
    for (int i = 0; i < 4; ++i)
        #pragma unroll
        for (int k = 0; k < 4; ++k) acc[i][k] = 0.f;

    for (int jt = 0; jt < 64; ++jt) {
        __syncthreads();
        #pragma unroll
        for (int r = 0; r < 4; ++r) {
            int idx = r * 256 + tid;
            int c   = idx >> 4;
            int j4  = (idx & 15) << 2;
            *(float4*)&kj[c][j4] = *(const float4*)(K  + (size_t)c * 4096 + jt * 64 + j4);
            *(float4*)&bj[c][j4] = *(const float4*)(Bt + (size_t)c * 4096 + jt * 64 + j4);
        }
        __syncthreads();

        // S2[m][j] = sum_c q[c][m] k[c][j];  m = ty*4+i, j = tx*4+k
        float s[4][4];
        #pragma unroll
        for (int i = 0; i < 4; ++i)
            #pragma unroll
            for (int k = 0; k < 4; ++k) s[i][k] = 0.f;

        #pragma unroll 8
        for (int c = 0; c < 64; ++c) {
            float qa[4], ka[4];
            load4(qa, *(const float4*)&qm[c][ty * 4]);
            load4(ka, *(const float4*)&kj[c][tx * 4]);
            #pragma unroll
            for (int i = 0; i < 4; ++i)
                #pragma unroll
                for (int k = 0; k < 4; ++k)
                    s[i][k] = fmaf(qa[i], ka[k], s[i][k]);
        }

        #pragma unroll
        for (int i = 0; i < 4; ++i) {
            float4 wv;
            wv.x = __expf(s[i][0] * 0.125f - Mv[i]) * Li[i];
            wv.y = __expf(s[i][1] * 0.125f - Mv[i]) * Li[i];
            wv.z = __expf(s[i][2] * 0.125f - Mv[i]) * Li[i];
            wv.w = __expf(s[i][3] * 0.125f - Mv[i]) * Li[i];
            *(float4*)&w2[ty * 4 + i][tx * 4] = wv;
        }
        __syncthreads();

        // acc[ci][mk] += sum_j bj[ty*4+ci][j] * w2[tx*4+mk][j]
        #pragma unroll 4
        for (int j4 = 0; j4 < 16; ++j4) {
            float ba4[4][4], wa4[4][4];
            #pragma unroll
            for (int u = 0; u < 4; ++u) {
                load4(ba4[u], *(const float4*)&bj[ty * 4 + u][j4 * 4]);
                load4(wa4[u], *(const float4*)&w2[tx * 4 + u][j4 * 4]);
            }
            #pragma unroll
            for (int ci = 0; ci < 4; ++ci)
                #pragma unroll
                for (int mk = 0; mk < 4; ++mk) {
                    acc[ci][mk] = fmaf(ba4[ci][0], wa4[mk][0], acc[ci][mk]);
                    acc[ci][mk] = fmaf(ba4[ci][1], wa4[mk][1], acc[ci][mk]);
                    acc[ci][mk] = fmaf(ba4[ci][2], wa4[mk][2], acc[ci][mk]);
                    acc[ci][mk] = fmaf(ba4[ci][3], wa4[mk][3], acc[ci][mk]);
                }
        }
    }

    #pragma unroll
    for (int i = 0; i < 4; ++i)
        *(float4*)(OutR + (size_t)(ty * 4 + i) * 4096 + mt * 64 + tx * 4) =
            make_float4(acc[i][0], acc[i][1], acc[i][2], acc[i][3]);
}

// ------------------------------------------------------------------- k_out1
// OutR[c][m] += sum_j P[j][m] * A[c][j]
__global__ __launch_bounds__(256) void k_out1(float* __restrict__ ws)
{
    const int tid = threadIdx.x;
    const int mt  = blockIdx.x & 63;
    const int br  = blockIdx.x >> 6;

    const float* Q  = ws + QOFF + (size_t)br * BRS;
    const float* K  = ws + KOFF + (size_t)br * BRS;
    const float* A  = ws + AOFF + (size_t)br * BRS;
    const float* Ms = ws + MOFF + (size_t)br * 4096;
    const float* Ls = ws + LOFF + (size_t)br * 4096;
    float* OutR     = ws + OOFF + (size_t)br * BRS;

    __shared__ float km[64][68];   // k columns at this m-tile (persistent)
    __shared__ float qj[64][68];
    __shared__ float aj[64][68];
    __shared__ float w1[64][68];   // [j_local][m_local]

    #pragma unroll
    for (int r = 0; r < 4; ++r) {
        int idx = r * 256 + tid;
        int c   = idx >> 4;
        int m4  = (idx & 15) << 2;
        *(float4*)&km[c][m4] = *(const float4*)(K + (size_t)c * 4096 + mt * 64 + m4);
    }

    const int tx = tid & 15, ty = tid >> 4;

    float acc[4][4];
    #pragma unroll
    for (int i = 0; i < 4; ++i)
        #pragma unroll
        for (int k = 0; k < 4; ++k) acc[i][k] = 0.f;

    for (int jt = 0; jt < 64; ++jt) {
        __syncthreads();
        #pragma unroll
        for (int r = 0; r < 4; ++r) {
            int idx = r * 256 + tid;
            int c   = idx >> 4;
            int j4  = (idx & 15) << 2;
            *(float4*)&qj[c][j4] = *(const float4*)(Q + (size_t)c * 4096 + jt * 64 + j4);
            *(float4*)&aj[c][j4] = *(const float4*)(A + (size_t)c * 4096 + jt * 64 + j4);
        }
        __syncthreads();

        float Mj[4], Lj[4];
        #pragma unroll
        for (int i = 0; i < 4; ++i) {
            Mj[i] = Ms[jt * 64 + ty * 4 + i];
            Lj[i] = 1.0f / Ls[jt * 64 + ty * 4 + i];
        }

        // S1[j][m] = sum_c q[c][j] k[c][m];  j = ty*4+i, m = tx*4+k
        float s[4][4];
        #pragma unroll
        for (int i = 0; i < 4; ++i)
            #pragma unroll
            for (int k = 0; k < 4; ++k) s[i][k] = 0.f;

        #pragma unroll 8
        for (int c = 0; c < 64; ++c) {
            float qa[4], ka[4];
            load4(qa, *(const float4*)&qj[c][ty * 4]);
            load4(ka, *(const float4*)&km[c][tx * 4]);
            #pragma unroll
            for (int i = 0; i < 4; ++i)
                #pragma unroll
                for (int k = 0; k < 4; ++k)
                    s[i][k] = fmaf(qa[i], ka[k], s[i][k]);
        }

        #pragma unroll
        for (int i = 0; i < 4; ++i) {
            float4 wv;
            wv.x = __expf(s[i][0] * 0.125f - Mj[i]) * Lj[i];
            wv.y = __expf(s[i][1] * 0.125f - Mj[i]) * Lj[i];
            wv.z = __expf(s[i][2] * 0.125f - Mj[i]) * Lj[i];
            wv.w = __expf(s[i][3] * 0.125f - Mj[i]) * Lj[i];
            *(float4*)&w1[ty * 4 + i][tx * 4] = wv;
        }
        __syncthreads();

        // acc[ci][mk] += sum_j aj[ty*4+ci][j] * w1[j][tx*4+mk]
        #pragma unroll 4
        for (int j4 = 0; j4 < 16; ++j4) {
            float aa4[4][4], wrow[4][4];
            #pragma unroll
            for (int u = 0; u < 4; ++u)
                load4(aa4[u], *(const float4*)&aj[ty * 4 + u][j4 * 4]);
            #pragma unroll
            for (int jj = 0; jj < 4; ++jj)
                load4(wrow[jj], *(const float4*)&w1[j4 * 4 + jj][tx * 4]);
            #pragma unroll
            for (int ci = 0; ci < 4; ++ci)
                #pragma unroll
                for (int mk = 0; mk < 4; ++mk) {
                    acc[ci][mk] = fmaf(aa4[ci][0], wrow[0][mk], acc[ci][mk]);
                    acc[ci][mk] = fmaf(aa4[ci][1], wrow[1][mk], acc[ci][mk]);
                    acc[ci][mk] = fmaf(aa4[ci][2], wrow[2][mk], acc[ci][mk]);
                    acc[ci][mk] = fmaf(aa4[ci][3], wrow[3][mk], acc[ci][mk]);
                }
        }
    }

    #pragma unroll
    for (int i = 0; i < 4; ++i) {
        float4* p = (float4*)(OutR + (size_t)(ty * 4 + i) * 4096 + mt * 64 + tx * 4);
        float4 old = *p;
        *p = make_float4(old.x + acc[i][0], old.y + acc[i][1],
                         old.z + acc[i][2], old.w + acc[i][3]);
    }
}

// --------------------------------------------------------------- k_conv_out
__global__ __launch_bounds__(256) void k_conv_out(
    const float* __restrict__ ws,
    const float* __restrict__ Wo, const float* __restrict__ bo,
    float* __restrict__ out)
{
    const int tid  = threadIdx.x;
    const int blk  = blockIdx.x;
    const int wseg = blk & 1;
    const int h    = (blk >> 1) & 127;
    const int b    = blk >> 8;

    const int gi = h >> 6, i = h & 63;
    const int br = b * 4 + gi * 2 + wseg;
    const float* OutR = ws + OOFF + (size_t)br * BRS;

    __shared__ float os[64][68];
    #pragma unroll
    for (int r = 0; r < 4; ++r) {
        int idx = r * 256 + tid;
        int c   = idx >> 4;
        int w4  = (idx & 15) << 2;
        *(float4*)&os[c][w4] = *(const float4*)(OutR + (size_t)c * 4096 + i * 64 + w4);
    }
    __syncthreads();

    const int oc = tid & 63, wq = tid >> 6;
    float acc[16];
    const float bias = bo[oc];
    #pragma unroll
    for (int w = 0; w < 16; ++w) acc[w] = bias;

    #pragma unroll 8
    for (int c = 0; c < 64; ++c) {
        const float wv = Wo[oc * 64 + c];
        #pragma unroll
        for (int w = 0; w < 16; ++w)
            acc[w] = fmaf(wv, os[c][wq * 16 + w], acc[w]);
    }

    float* op = out + ((size_t)b * 64 + oc) * 16384 + (size_t)h * 128 + wseg * 64 + wq * 16;
    #pragma unroll
    for (int w4 = 0; w4 < 4; ++w4)
        *(float4*)(op + w4 * 4) =
            make_float4(acc[w4*4], acc[w4*4+1], acc[w4*4+2], acc[w4*4+3]);
}

// -------------------------------------------------------------------- launch
extern "C" void kernel_launch(void* const* d_in, const int* in_sizes, int n_in,
                              void* d_out, int out_size, void* d_ws, size_t ws_size,
                              hipStream_t stream)
{
    const float* x  = (const float*)d_in[0];
    const float* Wq = (const float*)d_in[1];
    const float* bq = (const float*)d_in[2];
    const float* Wk = (const float*)d_in[3];
    const float* bk = (const float*)d_in[4];
    const float* Wa = (const float*)d_in[5];
    const float* ba = (const float*)d_in[6];
    const float* Wb = (const float*)d_in[7];
    const float* bb = (const float*)d_in[8];
    const float* Wo = (const float*)d_in[9];
    const float* bo = (const float*)d_in[10];
    float* ws  = (float*)d_ws;
    float* out = (float*)d_out;

    hipLaunchKernelGGL(k_conv_in, dim3(512), dim3(256), 0, stream,
                       x, Wq, bq, Wk, bk, Wa, ba, Wb, bb, ws);
    hipLaunchKernelGGL(k_stats,   dim3(512), dim3(256), 0, stream, ws);
    hipLaunchKernelGGL(k_out2,    dim3(512), dim3(256), 0, stream, ws);
    hipLaunchKernelGGL(k_out1,    dim3(512), dim3(256), 0, stream, ws);
    hipLaunchKernelGGL(k_conv_out, dim3(512), dim3(256), 0, stream,
                       ws, Wo, bo, out);
}

// Round 2
// 460.435 us; speedup vs baseline: 3.0789x; 3.0789x over previous
//
#include <hip/hip_runtime.h>

// RegionSeparatedAttention on MI355X — round 1: bf16 MFMA (32x32x16).
//
// Layouts in ws (all per region br = b*4 + gi*2 + gj, n = local row*64+col):
//   Qp,Kp : bf16 [8][4096 n][64 c]   pixel-major  (A/B frags contiguous)
//   Acm,Bcm: bf16 [8][64 c][4096 j]  channel-major (out-MFMA B-frags contiguous)
//   Mst,Lst: f32 [8][4096]           row max / 1/rowsum of softmax
//   OutP  : f32 [8][4096 n][64 c]    pixel-major attention output
//
// k_attn per (br, m-tile 64): waves (wm: m-sub-32, wj: j-interleave).
//   D1[j][m]=S[j][m] (A=Qp[j], B=Kp[m]),  D2[j][m]=S[m][j] (A=Kp[j], B=Qp[m])
//   G1[m][j]=exp(D1/8-M[j])*Linv[j], G2[m][j]=exp(D2/8-M[m])*Linv[m]
//   OutT[m][c] += G1 x Acm^T + G2 x Bcm^T   (wave-private LDS transpose, no
//   K-loop barriers; cross-wj reduce once at epilogue).

typedef __attribute__((ext_vector_type(8)))  short bf16x8;
typedef __attribute__((ext_vector_type(16))) float f32x16;

#define MFMA32(a, b, c) __builtin_amdgcn_mfma_f32_32x32x16_bf16(a, b, c, 0, 0, 0)

constexpr int REG_ELEMS = 4096 * 64;       // elements per region per tensor
// byte offsets in ws
constexpr size_t QP_OFF  = 0;              // bf16 8*262144 = 4 MB
constexpr size_t KP_OFF  = 4u  << 20;
constexpr size_t ACM_OFF = 8u  << 20;
constexpr size_t BCM_OFF = 12u << 20;
constexpr size_t MST_OFF = 16u << 20;      // f32 8*4096 = 128 KB
constexpr size_t LST_OFF = (16u << 20) + (128u << 10);
constexpr size_t OUTP_OFF= 17u << 20;      // f32 8*262144 = 8 MB

__device__ __forceinline__ short f2bf(float f) {
    union { float f; unsigned u; } v; v.f = f;
    unsigned r = v.u + 0x7fffu + ((v.u >> 16) & 1u);
    return (short)(r >> 16);
}

__device__ __forceinline__ f32x16 zero16() {
    f32x16 z;
    #pragma unroll
    for (int i = 0; i < 16; ++i) z[i] = 0.f;
    return z;
}

// ---------------------------------------------------------------- k_conv_in
// block = (b, h, wseg): 64-pixel row segment; 4 convs; Q,K transposed to
// pixel-major via LDS, A,B stored channel-major.
__global__ __launch_bounds__(256) void k_conv_in(
    const float* __restrict__ x,
    const float* __restrict__ Wq, const float* __restrict__ bq,
    const float* __restrict__ Wk, const float* __restrict__ bk,
    const float* __restrict__ Wa, const float* __restrict__ ba,
    const float* __restrict__ Wb, const float* __restrict__ bb,
    char* __restrict__ ws)
{
    const int tid  = threadIdx.x;
    const int blk  = blockIdx.x;
    const int wseg = blk & 1;
    const int h    = (blk >> 1) & 127;
    const int b    = blk >> 8;
    const int br   = b * 4 + (h >> 6) * 2 + wseg;
    const int n0   = (h & 63) * 64;

    __shared__ float xs[64][68];
    __shared__ short trans[2][64][72];

    const float* xp = x + ((size_t)b * 64 * 16384) + (size_t)h * 128 + wseg * 64;
    #pragma unroll
    for (int r = 0; r < 4; ++r) {
        int idx = r * 256 + tid;
        int c   = idx >> 4;
        int w4  = (idx & 15) << 2;
        *(float4*)&xs[c][w4] = *(const float4*)(xp + (size_t)c * 16384 + w4);
    }
    __syncthreads();

    const int mat = tid >> 6;
    const int oc  = tid & 63;
    const float* Wsel = (mat == 0) ? Wq : (mat == 1) ? Wk : (mat == 2) ? Wa : Wb;
    const float* bsel = (mat == 0) ? bq : (mat == 1) ? bk : (mat == 2) ? ba : bb;

    float acc[64];
    const float bias = bsel[oc];
    #pragma unroll
    for (int w = 0; w < 64; ++w) acc[w] = bias;

    #pragma unroll 8
    for (int c = 0; c < 64; ++c) {
        const float wv = Wsel[oc * 64 + c];
        #pragma unroll
        for (int w = 0; w < 64; ++w) acc[w] = fmaf(wv, xs[c][w], acc[w]);
    }

    if (mat >= 2) {
        // channel-major bf16 store
        short tmp[64];
        #pragma unroll
        for (int w = 0; w < 64; ++w) tmp[w] = f2bf(acc[w]);
        short* op = (short*)(ws + (mat == 2 ? ACM_OFF : BCM_OFF))
                    + (size_t)br * REG_ELEMS + (size_t)oc * 4096 + n0;
        #pragma unroll
        for (int w8 = 0; w8 < 8; ++w8)
            *(uint4*)(op + w8 * 8) = *(uint4*)&tmp[w8 * 8];
    } else {
        #pragma unroll
        for (int w = 0; w < 64; ++w) trans[mat][w][oc] = f2bf(acc[w]);
    }
    __syncthreads();

    // cooperative pixel-major store of Q,K: 2 mats * 64 rows * 128 B
    #pragma unroll
    for (int rep = 0; rep < 4; ++rep) {
        int idx  = rep * 256 + tid;
        int mat2 = idx >> 9;
        int row  = (idx >> 3) & 63;
        int seg  = idx & 7;
        short* dst = (short*)(ws + (mat2 ? KP_OFF : QP_OFF))
                     + (size_t)br * REG_ELEMS + (size_t)(n0 + row) * 64 + seg * 8;
        *(uint4*)dst = *(uint4*)&trans[mat2][row][seg * 8];
    }
}

// ------------------------------------------------------------------ k_stats
// block = (br, n-tile 64). waves: wn = n-sub-32, wm = m-interleave.
// Online softmax row stats of S[n][m] over all m.
__global__ __launch_bounds__(256) void k_stats(char* __restrict__ ws)
{
    const int tid  = threadIdx.x;
    const int br   = blockIdx.x & 7;
    const int nt   = blockIdx.x >> 3;
    const int lane = tid & 63;
    const int w    = tid >> 6;
    const int wn   = w & 1;
    const int wm   = w >> 1;
    const int col  = lane & 31;
    const int l5   = lane >> 5;

    const short* Qb = (const short*)(ws + QP_OFF) + (size_t)br * REG_ELEMS;
    const short* Kb = (const short*)(ws + KP_OFF) + (size_t)br * REG_ELEMS;

    // persistent A-frags: rows n = nt*64 + wn*32 + col
    bf16x8 afr[4];
    const short* qrow = Qb + (size_t)(nt * 64 + wn * 32 + col) * 64 + l5 * 8;
    #pragma unroll
    for (int s = 0; s < 4; ++s) afr[s] = *(const bf16x8*)(qrow + s * 16);

    float mx[16], sm[16];
    #pragma unroll
    for (int r = 0; r < 16; ++r) { mx[r] = -3.0e38f; sm[r] = 0.f; }

    for (int mt = wm; mt < 128; mt += 2) {
        const short* krow = Kb + (size_t)(mt * 32 + col) * 64 + l5 * 8;
        f32x16 d = zero16();
        #pragma unroll
        for (int s = 0; s < 4; ++s) {
            bf16x8 bfr = *(const bf16x8*)(krow + s * 16);
            d = MFMA32(afr[s], bfr, d);
        }
        #pragma unroll
        for (int r = 0; r < 16; ++r) {
            float xv = d[r] * 0.125f;
            float dd = xv - mx[r];
            float t  = __expf(-fabsf(dd));
            bool  g  = dd > 0.f;
            sm[r] = g ? fmaf(sm[r], t, 1.f) : (sm[r] + t);
            mx[r] = g ? xv : mx[r];
        }
    }

    // reduce across the 32 cols (lanes within each half)
    #pragma unroll
    for (int off = 1; off < 32; off <<= 1) {
        #pragma unroll
        for (int r = 0; r < 16; ++r) {
            float om = __shfl_xor(mx[r], off);
            float os = __shfl_xor(sm[r], off);
            float nm = fmaxf(mx[r], om);
            sm[r] = sm[r] * __expf(mx[r] - nm) + os * __expf(om - nm);
            mx[r] = nm;
        }
    }

    __shared__ float redM[2][64], redS[2][64];
    if (col == 0) {
        #pragma unroll
        for (int r = 0; r < 16; ++r) {
            int ln = wn * 32 + (r & 3) + 8 * (r >> 2) + 4 * l5;
            redM[wm][ln] = mx[r];
            redS[wm][ln] = sm[r];
        }
    }
    __syncthreads();
    if (tid < 64) {
        float m0 = redM[0][tid], m1 = redM[1][tid];
        float s0 = redS[0][tid], s1 = redS[1][tid];
        float nm = fmaxf(m0, m1);
        float L  = s0 * __expf(m0 - nm) + s1 * __expf(m1 - nm);
        float* Mst = (float*)(ws + MST_OFF) + (size_t)br * 4096;
        float* Lst = (float*)(ws + LST_OFF) + (size_t)br * 4096;
        Mst[nt * 64 + tid] = nm;
        Lst[nt * 64 + tid] = 1.0f / L;
    }
}

// ------------------------------------------------------------------- k_attn
__global__ __launch_bounds__(256) void k_attn(char* __restrict__ ws)
{
    const int tid  = threadIdx.x;
    const int br   = blockIdx.x & 7;
    const int mt   = blockIdx.x >> 3;      // 0..63, m-tile of 64
    const int lane = tid & 63;
    const int w    = tid >> 6;
    const int wm   = w & 1;                // m-sub-32
    const int wj   = w >> 1;               // j interleave
    const int col  = lane & 31;
    const int l5   = lane >> 5;

    const short* Qb  = (const short*)(ws + QP_OFF)  + (size_t)br * REG_ELEMS;
    const short* Kb  = (const short*)(ws + KP_OFF)  + (size_t)br * REG_ELEMS;
    const short* Ab  = (const short*)(ws + ACM_OFF) + (size_t)br * REG_ELEMS;
    const short* Bb  = (const short*)(ws + BCM_OFF) + (size_t)br * REG_ELEMS;
    const float* Mst = (const float*)(ws + MST_OFF) + (size_t)br * 4096;
    const float* Lst = (const float*)(ws + LST_OFF) + (size_t)br * 4096;
    float* OutP      = (float*)(ws + OUTP_OFF)      + (size_t)br * REG_ELEMS;

    __shared__ char smem[20480];
    short (*wlds)[2][32][40] = (short(*)[2][32][40])smem;   // [wave][G1/G2][m][j+pad]
    float (*red)[32][68]     = (float(*)[32][68])smem;      // epilogue reuse

    const int mrow = mt * 64 + wm * 32 + col;
    // persistent B-frags (cols m): Kp[m][c], Qp[m][c]
    bf16x8 kmf[4], qmf[4];
    {
        const short* kr = Kb + (size_t)mrow * 64 + l5 * 8;
        const short* qr = Qb + (size_t)mrow * 64 + l5 * 8;
        #pragma unroll
        for (int s = 0; s < 4; ++s) {
            kmf[s] = *(const bf16x8*)(kr + s * 16);
            qmf[s] = *(const bf16x8*)(qr + s * 16);
        }
    }
    const float Mm = Mst[mrow];
    const float Lm = Lst[mrow];

    f32x16 acc0 = zero16(), acc1 = zero16();

    for (int jt = wj; jt < 128; jt += 2) {
        // S-MFMAs: D1[j][m] = S[j][m], D2[j][m] = S[m][j]
        const short* qjr = Qb + (size_t)(jt * 32 + col) * 64 + l5 * 8;
        const short* kjr = Kb + (size_t)(jt * 32 + col) * 64 + l5 * 8;
        f32x16 d1 = zero16(), d2 = zero16();
        #pragma unroll
        for (int s = 0; s < 4; ++s) {
            bf16x8 qj = *(const bf16x8*)(qjr + s * 16);
            bf16x8 kj = *(const bf16x8*)(kjr + s * 16);
            d1 = MFMA32(qj, kmf[s], d1);
            d2 = MFMA32(kj, qmf[s], d2);
        }

        // j-stats for G1 (rows j = jt*32 + 8q + 4*l5 + 0..3)
        float4 Mq[4], Lq[4];
        #pragma unroll
        for (int q = 0; q < 4; ++q) {
            Mq[q] = *(const float4*)(Mst + jt * 32 + 8 * q + 4 * l5);
            Lq[q] = *(const float4*)(Lst + jt * 32 + 8 * q + 4 * l5);
        }

        // weights -> wave-private LDS (G[m][j] layout)
        #pragma unroll
        for (int q = 0; q < 4; ++q) {
            const float* mq = (const float*)&Mq[q];
            const float* lq = (const float*)&Lq[q];
            union { ushort4 v; short s[4]; } p1, p2;
            #pragma unroll
            for (int rr = 0; rr < 4; ++rr) {
                float e1 = __expf(d1[q * 4 + rr] * 0.125f - mq[rr]) * lq[rr];
                float e2 = __expf(d2[q * 4 + rr] * 0.125f - Mm) * Lm;
                p1.s[rr] = f2bf(e1);
                p2.s[rr] = f2bf(e2);
            }
            int jo = 8 * q + 4 * l5;
            *(ushort4*)&wlds[w][0][col][jo] = p1.v;
            *(ushort4*)&wlds[w][1][col][jo] = p2.v;
        }
        // same-wave LDS RAW: compiler inserts lgkmcnt wait; no barrier needed.

        // out-MFMAs: OutT[m][c] += G1 x Acm^T + G2 x Bcm^T
        #pragma unroll
        for (int k16 = 0; k16 < 2; ++k16) {
            bf16x8 a1 = *(const bf16x8*)&wlds[w][0][col][k16 * 16 + l5 * 8];
            bf16x8 a2 = *(const bf16x8*)&wlds[w][1][col][k16 * 16 + l5 * 8];
            const int jb = jt * 32 + k16 * 16 + l5 * 8;
            {
                bf16x8 bA = *(const bf16x8*)(Ab + (size_t)col * 4096 + jb);
                bf16x8 bB = *(const bf16x8*)(Bb + (size_t)col * 4096 + jb);
                acc0 = MFMA32(a1, bA, acc0);
                acc0 = MFMA32(a2, bB, acc0);
            }
            {
                bf16x8 bA = *(const bf16x8*)(Ab + (size_t)(32 + col) * 4096 + jb);
                bf16x8 bB = *(const bf16x8*)(Bb + (size_t)(32 + col) * 4096 + jb);
                acc1 = MFMA32(a1, bA, acc1);
                acc1 = MFMA32(a2, bB, acc1);
            }
        }
    }

    // epilogue: reduce wj pairs via LDS, store OutP pixel-major
    __syncthreads();
    if (wj == 1) {
        #pragma unroll
        for (int r = 0; r < 16; ++r) {
            int ml = (r & 3) + 8 * (r >> 2) + 4 * l5;
            red[wm][ml][col]      = acc0[r];
            red[wm][ml][32 + col] = acc1[r];
        }
    }
    __syncthreads();
    if (wj == 0) {
        #pragma unroll
        for (int r = 0; r < 16; ++r) {
            int ml = (r & 3) + 8 * (r >> 2) + 4 * l5;
            float v0 = acc0[r] + red[wm][ml][col];
            float v1 = acc1[r] + red[wm][ml][32 + col];
            float* orow = OutP + (size_t)(mt * 64 + wm * 32 + ml) * 64;
            orow[col]      = v0;
            orow[32 + col] = v1;
        }
    }
}

// --------------------------------------------------------------- k_conv_out
__global__ __launch_bounds__(256) void k_conv_out(
    const char* __restrict__ ws,
    const float* __restrict__ Wo, const float* __restrict__ bo,
    float* __restrict__ out)
{
    const int tid  = threadIdx.x;
    const int blk  = blockIdx.x;
    const int wseg = blk & 1;
    const int h    = (blk >> 1) & 127;
    const int b    = blk >> 8;
    const int br   = b * 4 + (h >> 6) * 2 + wseg;
    const int n0   = (h & 63) * 64;

    const float* OutP = (const float*)(ws + OUTP_OFF) + (size_t)br * REG_ELEMS;

    __shared__ float xs[64][68];   // [n_local][c]
    #pragma unroll
    for (int rep = 0; rep < 4; ++rep) {
        int idx = rep * 256 + tid;
        int row = idx >> 4;
        int c4  = (idx & 15) << 2;
        *(float4*)&xs[row][c4] = *(const float4*)(OutP + (size_t)(n0 + row) * 64 + c4);
    }
    __syncthreads();

    const int oc = tid & 63, nq = tid >> 6;
    float acc[16];
    const float bias = bo[oc];
    #pragma unroll
    for (int i = 0; i < 16; ++i) acc[i] = bias;

    #pragma unroll 8
    for (int c = 0; c < 64; ++c) {
        const float wv = Wo[oc * 64 + c];
        #pragma unroll
        for (int i = 0; i < 16; ++i)
            acc[i] = fmaf(wv, xs[nq * 16 + i][c], acc[i]);
    }

    float* op = out + ((size_t)b * 64 + oc) * 16384 + (size_t)h * 128 + wseg * 64 + nq * 16;
    #pragma unroll
    for (int i4 = 0; i4 < 4; ++i4)
        *(float4*)(op + i4 * 4) =
            make_float4(acc[i4*4], acc[i4*4+1], acc[i4*4+2], acc[i4*4+3]);
}

// -------------------------------------------------------------------- launch
extern "C" void kernel_launch(void* const* d_in, const int* in_sizes, int n_in,
                              void* d_out, int out_size, void* d_ws, size_t ws_size,
                              hipStream_t stream)
{
    const float* x  = (const float*)d_in[0];
    const float* Wq = (const float*)d_in[1];
    const float* bq = (const float*)d_in[2];
    const float* Wk = (const float*)d_in[3];
    const float* bk = (const float*)d_in[4];
    const float* Wa = (const float*)d_in[5];
    const float* ba = (const float*)d_in[6];
    const float* Wb = (const float*)d_in[7];
    const float* bb = (const float*)d_in[8];
    const float* Wo = (const float*)d_in[9];
    const float* bo = (const float*)d_in[10];
    char* ws   = (char*)d_ws;
    float* out = (float*)d_out;

    hipLaunchKernelGGL(k_conv_in,  dim3(512), dim3(256), 0, stream,
                       x, Wq, bq, Wk, bk, Wa, ba, Wb, bb, ws);
    hipLaunchKernelGGL(k_stats,    dim3(512), dim3(256), 0, stream, ws);
    hipLaunchKernelGGL(k_attn,     dim3(512), dim3(256), 0, stream, ws);
    hipLaunchKernelGGL(k_conv_out, dim3(512), dim3(256), 0, stream,
                       ws, Wo, bo, out);
}

// Round 3
// 433.504 us; speedup vs baseline: 3.2701x; 1.0621x over previous
//
#include <hip/hip_runtime.h>

// RegionSeparatedAttention on MI355X — round 2: no-max softmax (exp2-folded),
// perm-packed bf16 weights, 4 blocks/CU, bf16 OutP, MFMA conv_out.
//
// Numerics: S' = (q~ . k) where q~ = (Wq x + bq) * 0.125*log2(e).  Then
// softmax_m exp(S/8) == 2^(S' - F[row]) with F = log2(sum_m 2^S').  No max
// subtraction: std(S/8) ~ 1.4, overflow needs 60 sigma.
//
// Layouts in ws (per region br = b*4 + gi*2 + gj):
//   Qp,Kp  : bf16 [8][4096 n][64 c]  pixel-major (Q pre-scaled)
//   Acm,Bcm: bf16 [8][64 c][4096 j]  channel-major
//   F      : f32  [8][4096]          log2 of softmax row sum
//   OutP   : bf16 [8][4096 n][64 c]  pixel-major attention output

typedef __attribute__((ext_vector_type(8)))  short bf16x8;
typedef __attribute__((ext_vector_type(16))) float f32x16;

#define MFMA32(a, b, c) __builtin_amdgcn_mfma_f32_32x32x16_bf16(a, b, c, 0, 0, 0)

constexpr int REG_ELEMS = 4096 * 64;
constexpr size_t QP_OFF  = 0;
constexpr size_t KP_OFF  = 4u  << 20;
constexpr size_t ACM_OFF = 8u  << 20;
constexpr size_t BCM_OFF = 12u << 20;
constexpr size_t F_OFF   = 16u << 20;      // f32 8*4096
constexpr size_t OUTP_OFF= 17u << 20;      // bf16 8*262144 = 4 MB

constexpr float QSCALE = 0.18033688011112042f;  // 0.125 * log2(e)

__device__ __forceinline__ short f2bf(float f) {   // RNE (staging tensors)
    union { float f; unsigned u; } v; v.f = f;
    unsigned r = v.u + 0x7fffu + ((v.u >> 16) & 1u);
    return (short)(r >> 16);
}
__device__ __forceinline__ unsigned fbits(float f) {
    union { float f; unsigned u; } v; v.f = f; return v.u;
}
// pack two f32 -> two truncated bf16 in one v_perm_b32 (low = e0, high = e1)
__device__ __forceinline__ unsigned pack_trunc(float e0, float e1) {
    return __builtin_amdgcn_perm(fbits(e1), fbits(e0), 0x07060302u);
}
__device__ __forceinline__ f32x16 zero16() {
    f32x16 z;
    #pragma unroll
    for (int i = 0; i < 16; ++i) z[i] = 0.f;
    return z;
}

// ---------------------------------------------------------------- k_conv_in
// (round-1 structure, validated; only change: Q scaled by QSCALE)
__global__ __launch_bounds__(256) void k_conv_in(
    const float* __restrict__ x,
    const float* __restrict__ Wq, const float* __restrict__ bq,
    const float* __restrict__ Wk, const float* __restrict__ bk,
    const float* __restrict__ Wa, const float* __restrict__ ba,
    const float* __restrict__ Wb, const float* __restrict__ bb,
    char* __restrict__ ws)
{
    const int tid  = threadIdx.x;
    const int blk  = blockIdx.x;
    const int wseg = blk & 1;
    const int h    = (blk >> 1) & 127;
    const int b    = blk >> 8;
    const int br   = b * 4 + (h >> 6) * 2 + wseg;
    const int n0   = (h & 63) * 64;

    __shared__ float xs[64][68];
    __shared__ short trans[2][64][72];

    const float* xp = x + ((size_t)b * 64 * 16384) + (size_t)h * 128 + wseg * 64;
    #pragma unroll
    for (int r = 0; r < 4; ++r) {
        int idx = r * 256 + tid;
        int c   = idx >> 4;
        int w4  = (idx & 15) << 2;
        *(float4*)&xs[c][w4] = *(const float4*)(xp + (size_t)c * 16384 + w4);
    }
    __syncthreads();

    const int mat = tid >> 6;
    const int oc  = tid & 63;
    const float* Wsel = (mat == 0) ? Wq : (mat == 1) ? Wk : (mat == 2) ? Wa : Wb;
    const float* bsel = (mat == 0) ? bq : (mat == 1) ? bk : (mat == 2) ? ba : bb;

    float acc[64];
    const float bias = bsel[oc];
    #pragma unroll
    for (int w = 0; w < 64; ++w) acc[w] = bias;

    #pragma unroll 8
    for (int c = 0; c < 64; ++c) {
        const float wv = Wsel[oc * 64 + c];
        #pragma unroll
        for (int w = 0; w < 64; ++w) acc[w] = fmaf(wv, xs[c][w], acc[w]);
    }

    if (mat == 0) {
        #pragma unroll
        for (int w = 0; w < 64; ++w) acc[w] *= QSCALE;
    }

    if (mat >= 2) {
        short tmp[64];
        #pragma unroll
        for (int w = 0; w < 64; ++w) tmp[w] = f2bf(acc[w]);
        short* op = (short*)(ws + (mat == 2 ? ACM_OFF : BCM_OFF))
                    + (size_t)br * REG_ELEMS + (size_t)oc * 4096 + n0;
        #pragma unroll
        for (int w8 = 0; w8 < 8; ++w8)
            *(uint4*)(op + w8 * 8) = *(uint4*)&tmp[w8 * 8];
    } else {
        #pragma unroll
        for (int w = 0; w < 64; ++w) trans[mat][w][oc] = f2bf(acc[w]);
    }
    __syncthreads();

    #pragma unroll
    for (int rep = 0; rep < 4; ++rep) {
        int idx  = rep * 256 + tid;
        int mat2 = idx >> 9;
        int row  = (idx >> 3) & 63;
        int seg  = idx & 7;
        short* dst = (short*)(ws + (mat2 ? KP_OFF : QP_OFF))
                     + (size_t)br * REG_ELEMS + (size_t)(n0 + row) * 64 + seg * 8;
        *(uint4*)dst = *(uint4*)&trans[mat2][row][seg * 8];
    }
}

// ------------------------------------------------------------------ k_stats
// block = (br, n-tile 32); 4 waves interleave m-tiles.  F[n] = log2 sum_m 2^S'.
__global__ __launch_bounds__(256) void k_stats(char* __restrict__ ws)
{
    const int tid  = threadIdx.x;
    const int br   = blockIdx.x & 7;
    const int nt   = blockIdx.x >> 3;          // 0..127
    const int lane = tid & 63;
    const int w    = tid >> 6;
    const int col  = lane & 31;
    const int l5   = lane >> 5;

    const short* Qb = (const short*)(ws + QP_OFF) + (size_t)br * REG_ELEMS;
    const short* Kb = (const short*)(ws + KP_OFF) + (size_t)br * REG_ELEMS;

    bf16x8 afr[4];
    const short* qrow = Qb + (size_t)(nt * 32 + col) * 64 + l5 * 8;
    #pragma unroll
    for (int s = 0; s < 4; ++s) afr[s] = *(const bf16x8*)(qrow + s * 16);

    float sm[16];
    #pragma unroll
    for (int r = 0; r < 16; ++r) sm[r] = 0.f;

    for (int mt = w; mt < 128; mt += 4) {
        const short* krow = Kb + (size_t)(mt * 32 + col) * 64 + l5 * 8;
        f32x16 d = zero16();
        #pragma unroll
        for (int s = 0; s < 4; ++s) {
            bf16x8 bfr = *(const bf16x8*)(krow + s * 16);
            d = MFMA32(afr[s], bfr, d);
        }
        #pragma unroll
        for (int r = 0; r < 16; ++r) sm[r] += exp2f(d[r]);
    }

    #pragma unroll
    for (int off = 1; off < 32; off <<= 1)
        #pragma unroll
        for (int r = 0; r < 16; ++r) sm[r] += __shfl_xor(sm[r], off);

    __shared__ float redL[4][32];
    if (col == 0) {
        #pragma unroll
        for (int r = 0; r < 16; ++r)
            redL[w][(r & 3) + 8 * (r >> 2) + 4 * l5] = sm[r];
    }
    __syncthreads();
    if (tid < 32) {
        float L = redL[0][tid] + redL[1][tid] + redL[2][tid] + redL[3][tid];
        float* Fv = (float*)(ws + F_OFF) + (size_t)br * 4096;
        Fv[nt * 32 + tid] = log2f(L);
    }
}

// ------------------------------------------------------------------- k_attn
// block = (br, m-tile 32); 4 waves interleave j-tiles; epilogue LDS reduce.
__global__ __launch_bounds__(256, 4) void k_attn(char* __restrict__ ws)
{
    const int tid  = threadIdx.x;
    const int br   = blockIdx.x & 7;
    const int mt   = blockIdx.x >> 3;          // 0..127
    const int lane = tid & 63;
    const int w    = tid >> 6;                 // j-interleave
    const int col  = lane & 31;
    const int l5   = lane >> 5;

    const short* Qb  = (const short*)(ws + QP_OFF)  + (size_t)br * REG_ELEMS;
    const short* Kb  = (const short*)(ws + KP_OFF)  + (size_t)br * REG_ELEMS;
    const short* Ab  = (const short*)(ws + ACM_OFF) + (size_t)br * REG_ELEMS;
    const short* Bb  = (const short*)(ws + BCM_OFF) + (size_t)br * REG_ELEMS;
    const float* Fv  = (const float*)(ws + F_OFF)   + (size_t)br * 4096;
    short* OutPb     = (short*)(ws + OUTP_OFF)      + (size_t)br * REG_ELEMS;

    __shared__ __align__(16) char smem[34816];   // wlds (20480) / red (34816) union
    short (*wg)[32][40] = (short(*)[32][40])(smem + (size_t)w * 5120); // [g][m][j]

    const int mrow = mt * 32 + col;
    bf16x8 kmf[4], qmf[4];
    {
        const short* kr = Kb + (size_t)mrow * 64 + l5 * 8;
        const short* qr = Qb + (size_t)mrow * 64 + l5 * 8;
        #pragma unroll
        for (int s = 0; s < 4; ++s) {
            kmf[s] = *(const bf16x8*)(kr + s * 16);
            qmf[s] = *(const bf16x8*)(qr + s * 16);
        }
    }
    const float Fm = Fv[mrow];

    f32x16 acc0 = zero16(), acc1 = zero16();

    for (int jt = w; jt < 128; jt += 4) {
        const short* qjr = Qb + (size_t)(jt * 32 + col) * 64 + l5 * 8;
        const short* kjr = Kb + (size_t)(jt * 32 + col) * 64 + l5 * 8;
        f32x16 d1 = zero16(), d2 = zero16();
        #pragma unroll
        for (int s = 0; s < 4; ++s) {
            bf16x8 qj = *(const bf16x8*)(qjr + s * 16);
            bf16x8 kj = *(const bf16x8*)(kjr + s * 16);
            d1 = MFMA32(qj, kmf[s], d1);       // D1[j][m] = S'[j][m]
            d2 = MFMA32(kj, qmf[s], d2);       // D2[j][m] = S'[m][j]
        }

        #pragma unroll
        for (int q = 0; q < 4; ++q) {
            float4 Fq = *(const float4*)(Fv + jt * 32 + 8 * q + 4 * l5);
            unsigned w1a = pack_trunc(exp2f(d1[4*q+0] - Fq.x), exp2f(d1[4*q+1] - Fq.y));
            unsigned w1b = pack_trunc(exp2f(d1[4*q+2] - Fq.z), exp2f(d1[4*q+3] - Fq.w));
            unsigned w2a = pack_trunc(exp2f(d2[4*q+0] - Fm),   exp2f(d2[4*q+1] - Fm));
            unsigned w2b = pack_trunc(exp2f(d2[4*q+2] - Fm),   exp2f(d2[4*q+3] - Fm));
            const int jo = 8 * q + 4 * l5;
            *(unsigned*)&wg[0][col][jo]     = w1a;
            *(unsigned*)&wg[0][col][jo + 2] = w1b;
            *(unsigned*)&wg[1][col][jo]     = w2a;
            *(unsigned*)&wg[1][col][jo + 2] = w2b;
        }
        // same-wave LDS RAW: compiler inserts lgkmcnt wait; no barrier.

        #pragma unroll
        for (int k16 = 0; k16 < 2; ++k16) {
            bf16x8 a1 = *(const bf16x8*)&wg[0][col][k16 * 16 + l5 * 8];
            bf16x8 a2 = *(const bf16x8*)&wg[1][col][k16 * 16 + l5 * 8];
            const int jb = jt * 32 + k16 * 16 + l5 * 8;
            {
                bf16x8 bA = *(const bf16x8*)(Ab + (size_t)col * 4096 + jb);
                bf16x8 bB = *(const bf16x8*)(Bb + (size_t)col * 4096 + jb);
                acc0 = MFMA32(a1, bA, acc0);
                acc0 = MFMA32(a2, bB, acc0);
            }
            {
                bf16x8 bA = *(const bf16x8*)(Ab + (size_t)(32 + col) * 4096 + jb);
                bf16x8 bB = *(const bf16x8*)(Bb + (size_t)(32 + col) * 4096 + jb);
                acc1 = MFMA32(a1, bA, acc1);
                acc1 = MFMA32(a2, bB, acc1);
            }
        }
    }

    // epilogue: 4-wave reduce in LDS, pack bf16, store OutP pixel-major
    __syncthreads();
    float* red = (float*)smem;                 // [4][32][68]
    #pragma unroll
    for (int r = 0; r < 16; ++r) {
        int ml = (r & 3) + 8 * (r >> 2) + 4 * l5;
        red[((size_t)w * 32 + ml) * 68 + col]      = acc0[r];
        red[((size_t)w * 32 + ml) * 68 + 32 + col] = acc1[r];
    }
    __syncthreads();
    {
        const int nl = tid >> 3;
        const int c8 = (tid & 7) * 8;
        float v[8];
        #pragma unroll
        for (int i = 0; i < 8; ++i) v[i] = 0.f;
        #pragma unroll
        for (int ww = 0; ww < 4; ++ww) {
            const float* rp = red + ((size_t)ww * 32 + nl) * 68 + c8;
            #pragma unroll
            for (int i = 0; i < 8; ++i) v[i] += rp[i];
        }
        uint4 pk;
        pk.x = pack_trunc(v[0], v[1]);
        pk.y = pack_trunc(v[2], v[3]);
        pk.z = pack_trunc(v[4], v[5]);
        pk.w = pack_trunc(v[6], v[7]);
        *(uint4*)(OutPb + (size_t)(mt * 32 + nl) * 64 + c8) = pk;
    }
}

// --------------------------------------------------------------- k_conv_out
// block = (br, 32-pixel tile), 64 threads, pure-register MFMA.
__global__ __launch_bounds__(64) void k_conv_out(
    const char* __restrict__ ws,
    const float* __restrict__ Wo, const float* __restrict__ bo,
    float* __restrict__ out)
{
    const int lane = threadIdx.x;
    const int br   = blockIdx.x & 7;
    const int nt   = blockIdx.x >> 3;          // 0..127
    const int col  = lane & 31;
    const int l5   = lane >> 5;

    const short* OutPb = (const short*)(ws + OUTP_OFF) + (size_t)br * REG_ELEMS;

    // A-frags: rows n = nt*32 + col from pixel-major OutP
    bf16x8 afr[4];
    const short* arow = OutPb + (size_t)(nt * 32 + col) * 64 + l5 * 8;
    #pragma unroll
    for (int s = 0; s < 4; ++s) afr[s] = *(const bf16x8*)(arow + s * 16);

    // B-frags: Wo rows oc (f32 -> bf16)
    bf16x8 bw[2][4];
    #pragma unroll
    for (int oh = 0; oh < 2; ++oh) {
        const float* wrow = Wo + (size_t)(oh * 32 + col) * 64 + l5 * 8;
        #pragma unroll
        for (int s = 0; s < 4; ++s) {
            float4 f0 = *(const float4*)(wrow + s * 16);
            float4 f1 = *(const float4*)(wrow + s * 16 + 4);
            union { bf16x8 v; short sh[8]; } u;
            u.sh[0] = f2bf(f0.x); u.sh[1] = f2bf(f0.y);
            u.sh[2] = f2bf(f0.z); u.sh[3] = f2bf(f0.w);
            u.sh[4] = f2bf(f1.x); u.sh[5] = f2bf(f1.y);
            u.sh[6] = f2bf(f1.z); u.sh[7] = f2bf(f1.w);
            bw[oh][s] = u.v;
        }
    }

    f32x16 d0 = zero16(), d1 = zero16();
    #pragma unroll
    for (int s = 0; s < 4; ++s) {
        d0 = MFMA32(afr[s], bw[0][s], d0);
        d1 = MFMA32(afr[s], bw[1][s], d1);
    }

    const int b  = br >> 2;
    const int gi = (br >> 1) & 1;
    const int gj = br & 1;

    #pragma unroll
    for (int oh = 0; oh < 2; ++oh) {
        const int oc = oh * 32 + col;
        const float bias = bo[oc];
        const f32x16& d = oh ? d1 : d0;
        #pragma unroll
        for (int q = 0; q < 4; ++q) {
            int nloc = 8 * q + 4 * l5;              // + rr via regs
            int nreg = nt * 32 + nloc;
            int wp   = nreg & 63;
            int ip   = nreg >> 6;
            float4 v = make_float4(d[4*q+0] + bias, d[4*q+1] + bias,
                                   d[4*q+2] + bias, d[4*q+3] + bias);
            float* op = out + ((size_t)(b * 64 + oc)) * 16384
                        + (size_t)(gi * 64 + ip) * 128 + gj * 64 + wp;
            *(float4*)op = v;
        }
    }
}

// -------------------------------------------------------------------- launch
extern "C" void kernel_launch(void* const* d_in, const int* in_sizes, int n_in,
                              void* d_out, int out_size, void* d_ws, size_t ws_size,
                              hipStream_t stream)
{
    const float* x  = (const float*)d_in[0];
    const float* Wq = (const float*)d_in[1];
    const float* bq = (const float*)d_in[2];
    const float* Wk = (const float*)d_in[3];
    const float* bk = (const float*)d_in[4];
    const float* Wa = (const float*)d_in[5];
    const float* ba = (const float*)d_in[6];
    const float* Wb = (const float*)d_in[7];
    const float* bb = (const float*)d_in[8];
    const float* Wo = (const float*)d_in[9];
    const float* bo = (const float*)d_in[10];
    char* ws   = (char*)d_ws;
    float* out = (float*)d_out;

    hipLaunchKernelGGL(k_conv_in,  dim3(512),  dim3(256), 0, stream,
                       x, Wq, bq, Wk, bk, Wa, ba, Wb, bb, ws);
    hipLaunchKernelGGL(k_stats,    dim3(1024), dim3(256), 0, stream, ws);
    hipLaunchKernelGGL(k_attn,     dim3(1024), dim3(256), 0, stream, ws);
    hipLaunchKernelGGL(k_conv_out, dim3(1024), dim3(64),  0, stream,
                       ws, Wo, bo, out);
}

// Round 4
// 278.486 us; speedup vs baseline: 5.0905x; 1.5566x over previous
//
#include <hip/hip_runtime.h>

// RegionSeparatedAttention on MI355X — round 3: LDS-staged slabs (dense
// global_load_lds), swizzled layouts, path-split waves, folded softmax.
//
// Global layouts in ws (per region br = b*4 + gi*2 + gj), ALL pre-swizzled:
//   Qp,Kp : bf16 [8][4096 n][64 c] pixel-major rows, 16B-seg swizzle
//           seg_stored = seg ^ (n & 7)            (Q pre-scaled by QSCALE)
//   Atl,Btl: bf16 [8][128 jtile][64 c][32 j] tiles, seg swizzle
//           seg_stored = seg ^ ((c>>1) & 3)       (A gets *= Linv[j] in k_stats)
//   OutP  : bf16 [8][4096 n][64 c] pixel-major, UNswizzled
//
// k_attn block = (br, mt of 128 m): 8 waves = (wm 0..3) x (wj path 0..1).
//   wj=0: d1[j][m]=S'[j][m], weights 2^d1, acc += W x A'^T  (Linv folded in A')
//   wj=1: d2[j][m]=S'[m][j], weights 2^d2 (unnormalized), Lm accumulated
//         online from the same exps; acc scaled by 1/Lm at epilogue.
// Slab = 32 j: Q/K/A/B 4KB each staged to LDS (16 instr, 8 waves), dbuf,
// 1 barrier per slab. C->A-operand weight transpose via lane^32 shfl.

typedef __attribute__((ext_vector_type(8)))  short bf16x8;
typedef __attribute__((ext_vector_type(16))) float f32x16;

#define MFMA32(a, b, c) __builtin_amdgcn_mfma_f32_32x32x16_bf16(a, b, c, 0, 0, 0)

constexpr int REG_ELEMS = 4096 * 64;
constexpr size_t QP_OFF  = 0;
constexpr size_t KP_OFF  = 4u  << 20;
constexpr size_t ATL_OFF = 8u  << 20;
constexpr size_t BTL_OFF = 12u << 20;
constexpr size_t OUTP_OFF= 16u << 20;

constexpr float QSCALE = 0.18033688011112042f;  // 0.125 * log2(e)

__device__ __forceinline__ short f2bf(float f) {   // RNE
    union { float f; unsigned u; } v; v.f = f;
    unsigned r = v.u + 0x7fffu + ((v.u >> 16) & 1u);
    return (short)(r >> 16);
}
__device__ __forceinline__ float bf2f(short s) {
    union { unsigned u; float f; } v; v.u = ((unsigned)(unsigned short)s) << 16;
    return v.f;
}
__device__ __forceinline__ unsigned fbits(float f) {
    union { float f; unsigned u; } v; v.f = f; return v.u;
}
__device__ __forceinline__ unsigned pack_trunc(float e0, float e1) {
    return __builtin_amdgcn_perm(fbits(e1), fbits(e0), 0x07060302u);
}
__device__ __forceinline__ f32x16 zero16() {
    f32x16 z;
    #pragma unroll
    for (int i = 0; i < 16; ++i) z[i] = 0.f;
    return z;
}

typedef __attribute__((address_space(1))) const unsigned char as1_t;
typedef __attribute__((address_space(3))) unsigned char as3_t;
__device__ __forceinline__ void stage16(const void* g, void* l) {
    __builtin_amdgcn_global_load_lds((as1_t*)g, (as3_t*)l, 16, 0, 0);
}

// ---------------------------------------------------------------- k_conv_in
__global__ __launch_bounds__(256) void k_conv_in(
    const float* __restrict__ x,
    const float* __restrict__ Wq, const float* __restrict__ bq,
    const float* __restrict__ Wk, const float* __restrict__ bk,
    const float* __restrict__ Wa, const float* __restrict__ ba,
    const float* __restrict__ Wb, const float* __restrict__ bb,
    char* __restrict__ ws)
{
    const int tid  = threadIdx.x;
    const int blk  = blockIdx.x;
    const int wseg = blk & 1;
    const int h    = (blk >> 1) & 127;
    const int b    = blk >> 8;
    const int br   = b * 4 + (h >> 6) * 2 + wseg;
    const int n0   = (h & 63) * 64;

    __shared__ float xs[64][68];
    __shared__ short trans[2][64][72];

    const float* xp = x + ((size_t)b * 64 * 16384) + (size_t)h * 128 + wseg * 64;
    #pragma unroll
    for (int r = 0; r < 4; ++r) {
        int idx = r * 256 + tid;
        int c   = idx >> 4;
        int w4  = (idx & 15) << 2;
        *(float4*)&xs[c][w4] = *(const float4*)(xp + (size_t)c * 16384 + w4);
    }
    __syncthreads();

    const int mat = tid >> 6;
    const int oc  = tid & 63;
    const float* Wsel = (mat == 0) ? Wq : (mat == 1) ? Wk : (mat == 2) ? Wa : Wb;
    const float* bsel = (mat == 0) ? bq : (mat == 1) ? bk : (mat == 2) ? ba : bb;

    float acc[64];
    const float bias = bsel[oc];
    #pragma unroll
    for (int w = 0; w < 64; ++w) acc[w] = bias;

    #pragma unroll 8
    for (int c = 0; c < 64; ++c) {
        const float wv = Wsel[oc * 64 + c];
        #pragma unroll
        for (int w = 0; w < 64; ++w) acc[w] = fmaf(wv, xs[c][w], acc[w]);
    }

    if (mat == 0) {
        #pragma unroll
        for (int w = 0; w < 64; ++w) acc[w] *= QSCALE;
    }

    if (mat >= 2) {
        // tiled channel-major store: [tile][c 64][j 32], seg-swizzled
        short tmp[64];
        #pragma unroll
        for (int w = 0; w < 64; ++w) tmp[w] = f2bf(acc[w]);
        short* base = (short*)(ws + (mat == 2 ? ATL_OFF : BTL_OFF))
                      + (size_t)br * REG_ELEMS;
        const int sw = (oc >> 1) & 3;
        #pragma unroll
        for (int w8 = 0; w8 < 8; ++w8) {
            int tile = (n0 >> 5) + (w8 >> 2);
            int segp = (w8 & 3) ^ sw;
            *(uint4*)(base + (size_t)tile * 2048 + oc * 32 + segp * 8) =
                *(uint4*)&tmp[w8 * 8];
        }
    } else {
        #pragma unroll
        for (int w = 0; w < 64; ++w) trans[mat][w][oc] = f2bf(acc[w]);
    }
    __syncthreads();

    // pixel-major Q/K store with seg swizzle: seg' = seg ^ (row & 7)
    #pragma unroll
    for (int rep = 0; rep < 4; ++rep) {
        int idx  = rep * 256 + tid;
        int mat2 = idx >> 9;
        int row  = (idx >> 3) & 63;
        int seg  = idx & 7;
        short* dst = (short*)(ws + (mat2 ? KP_OFF : QP_OFF))
                     + (size_t)br * REG_ELEMS + (size_t)(n0 + row) * 64
                     + (seg ^ (row & 7)) * 8;
        *(uint4*)dst = *(uint4*)&trans[mat2][row][seg * 8];
    }
}

// ------------------------------------------------------------------ k_stats
// block = (br, nt of 128 n-rows). 8 waves = (wn 0..3) x (wi m-half 0..1).
// L[n] = sum_m 2^S'[n][m]; then A-tiles of this j-range scaled by 1/L.
__global__ __launch_bounds__(512, 2) void k_stats(char* __restrict__ ws)
{
    const int tid  = threadIdx.x;
    const int br   = blockIdx.x & 7;
    const int nt   = blockIdx.x >> 3;          // 0..31
    const int lane = tid & 63;
    const int w    = tid >> 6;
    const int wn   = w & 3;
    const int wi   = w >> 2;
    const int col  = lane & 31;
    const int l5   = lane >> 5;

    const short* Qb = (const short*)(ws + QP_OFF) + (size_t)br * REG_ELEMS;
    const char*  Kbb = ws + KP_OFF + (size_t)br * REG_ELEMS * 2;

    __shared__ __align__(16) char smem[34816];  // staging 32K | Lred 1K | Larr 512B

    // persistent A-frags (swizzled global): rows n = nt*128 + wn*32 + col
    const int nrow = nt * 128 + wn * 32 + col;
    bf16x8 afr[4];
    #pragma unroll
    for (int s = 0; s < 4; ++s)
        afr[s] = *(const bf16x8*)(Qb + (size_t)nrow * 64 + (((2*s+l5) ^ (col & 7)) * 8));

    float sm[16];
    #pragma unroll
    for (int r = 0; r < 16; ++r) sm[r] = 0.f;

    // stage slab 0 (128 m-rows = 16 KB; wave w covers 2 KB)
    {
        const char* g = Kbb + (size_t)w * 2048 + lane * 16;
        char* l = smem + w * 2048;
        stage16(g, l); stage16(g + 1024, l + 1024);
    }

    #pragma unroll 2
    for (int slab = 0; slab < 32; ++slab) {
        __syncthreads();   // slab ready (vmcnt drained), prev buffer free
        if (slab + 1 < 32) {
            const char* g = Kbb + (size_t)(slab + 1) * 16384 + w * 2048 + lane * 16;
            char* l = smem + ((slab + 1) & 1) * 16384 + w * 2048;
            stage16(g, l); stage16(g + 1024, l + 1024);
        }
        const short* Ks = (const short*)(smem + (slab & 1) * 16384);
        #pragma unroll
        for (int g2 = 0; g2 < 2; ++g2) {
            const int mtl = wi * 2 + g2;       // 32-row group within slab
            f32x16 d = zero16();
            #pragma unroll
            for (int s = 0; s < 4; ++s) {
                bf16x8 bf = *(const bf16x8*)(Ks + (mtl * 32 + col) * 64
                                             + ((2*s+l5) ^ (col & 7)) * 8);
                d = MFMA32(afr[s], bf, d);
            }
            #pragma unroll
            for (int r = 0; r < 16; ++r) sm[r] += exp2f(d[r]);
        }
    }

    // reduce over m: cols within 32-half, then wi pairs
    #pragma unroll
    for (int off = 1; off < 32; off <<= 1)
        #pragma unroll
        for (int r = 0; r < 16; ++r) sm[r] += __shfl_xor(sm[r], off);

    __syncthreads();
    float* Lred = (float*)(smem + 32768);      // [8][32]
    float* Larr = (float*)(smem + 33792);      // [128] = 1/L
    if (col == 0) {
        #pragma unroll
        for (int r = 0; r < 16; ++r)
            Lred[w * 32 + ((r & 3) + 8 * (r >> 2) + 4 * l5)] = sm[r];
    }
    __syncthreads();
    if (tid < 128) {
        int wn2 = tid >> 5, nl = tid & 31;
        float L = Lred[wn2 * 32 + nl] + Lred[(wn2 + 4) * 32 + nl];
        Larr[tid] = 1.0f / L;
    }
    __syncthreads();

    // scale A-tiles of this j-range in place (swizzle-aware)
    short* Ab = (short*)(ws + ATL_OFF) + (size_t)br * REG_ELEMS + (size_t)nt * 8192;
    #pragma unroll
    for (int rep = 0; rep < 2; ++rep) {
        int id = rep * 512 + tid;              // 0..1023 chunks of 16B
        int t = id >> 8, c = (id >> 2) & 63, s = id & 3;
        int sg = s ^ ((c >> 1) & 3);
        int jl = t * 32 + sg * 8;
        short* p = Ab + (size_t)t * 2048 + c * 32 + s * 8;
        uint4 v = *(uint4*)p;
        short* sp = (short*)&v;
        short o[8];
        #pragma unroll
        for (int e = 0; e < 8; ++e) o[e] = f2bf(bf2f(sp[e]) * Larr[jl + e]);
        *(uint4*)p = *(uint4*)o;
    }
}

// ------------------------------------------------------------------- k_attn
__global__ __launch_bounds__(512, 2) void k_attn(char* __restrict__ ws)
{
    const int tid  = threadIdx.x;
    const int br   = blockIdx.x & 7;
    const int mt   = blockIdx.x >> 3;          // 0..31, m-tile of 128
    const int lane = tid & 63;
    const int w    = tid >> 6;
    const int wm   = w & 3;                    // m-sub-32
    const int wj   = w >> 2;                   // path: 0 = G1*A', 1 = G2*B
    const int col  = lane & 31;
    const int l5   = lane >> 5;

    const char* Qbb = ws + QP_OFF  + (size_t)br * REG_ELEMS * 2;
    const char* Kbb = ws + KP_OFF  + (size_t)br * REG_ELEMS * 2;
    const char* Abb = ws + ATL_OFF + (size_t)br * REG_ELEMS * 2;
    const char* Bbb = ws + BTL_OFF + (size_t)br * REG_ELEMS * 2;
    short* OutPb    = (short*)(ws + OUTP_OFF) + (size_t)br * REG_ELEMS;

    __shared__ __align__(16) char smem[35328]; // staging 32K | red [128][68] f32 (34816) | Ltmp 512B

    // persistent m-frags: wj=0 needs K[mrow] (B-op of d1), wj=1 needs Q[mrow]
    const int mrow = mt * 128 + wm * 32 + col;
    const short* msrc = (const short*)(wj == 0 ? Kbb : Qbb) + (size_t)mrow * 64;
    bf16x8 mf[4];
    #pragma unroll
    for (int s = 0; s < 4; ++s)
        mf[s] = *(const bf16x8*)(msrc + ((2*s+l5) ^ (col & 7)) * 8);

    f32x16 accL = zero16(), accH = zero16();
    float Lp = 0.f;

    // this wave's staging source: [Q|K|A|B] x 2KB halves; lds off = w*2048
    const char* gsb = (w < 2) ? Qbb : (w < 4) ? Kbb : (w < 6) ? Abb : Bbb;
    const int goff = (w & 1) * 2048;

    {   // stage slab 0 (32 j = 16 KB)
        const char* g = gsb + goff + lane * 16;
        char* l = smem + w * 2048;
        stage16(g, l); stage16(g + 1024, l + 1024);
    }

    #pragma unroll 2
    for (int slab = 0; slab < 128; ++slab) {
        __syncthreads();
        if (slab + 1 < 128) {
            const char* g = gsb + (size_t)(slab + 1) * 4096 + goff + lane * 16;
            char* l = smem + ((slab + 1) & 1) * 16384 + w * 2048;
            stage16(g, l); stage16(g + 1024, l + 1024);
        }
        const char* sb = smem + (slab & 1) * 16384;
        const short* js = (const short*)(sb + (wj == 0 ? 0 : 4096));      // Q rows | K rows
        const short* ts = (const short*)(sb + (wj == 0 ? 8192 : 12288));  // A' | B tile

        // S-MFMA: d[j][m]
        f32x16 d = zero16();
        #pragma unroll
        for (int s = 0; s < 4; ++s) {
            bf16x8 a = *(const bf16x8*)(js + col * 64 + ((2*s+l5) ^ (col & 7)) * 8);
            d = MFMA32(a, mf[s], d);
        }

        // raw exp2 weights (no max, normalizers folded/deferred)
        float e[16];
        #pragma unroll
        for (int r = 0; r < 16; ++r) e[r] = exp2f(d[r]);
        if (wj == 1) {
            float t = 0.f;
            #pragma unroll
            for (int r = 0; r < 16; ++r) t += e[r];
            Lp += t;
        }
        unsigned Wp[8];
        #pragma unroll
        for (int q = 0; q < 4; ++q) {
            Wp[2*q]   = pack_trunc(e[4*q],   e[4*q+1]);
            Wp[2*q+1] = pack_trunc(e[4*q+2], e[4*q+3]);
        }

        // C-layout -> A-operand via lane^32 exchange; then out-MFMAs
        const bool hi = (l5 != 0);
        #pragma unroll
        for (int k16 = 0; k16 < 2; ++k16) {
            unsigned r0x = (unsigned)__shfl_xor((int)Wp[4*k16+0], 32);
            unsigned r0y = (unsigned)__shfl_xor((int)Wp[4*k16+1], 32);
            unsigned r1x = (unsigned)__shfl_xor((int)Wp[4*k16+2], 32);
            unsigned r1y = (unsigned)__shfl_xor((int)Wp[4*k16+3], 32);
            union { uint4 u; bf16x8 v; } fr;
            fr.u.x = hi ? r1x : Wp[4*k16+0];
            fr.u.y = hi ? r1y : Wp[4*k16+1];
            fr.u.z = hi ? Wp[4*k16+2] : r0x;
            fr.u.w = hi ? Wp[4*k16+3] : r0y;

            const int swz = ((2*k16 + l5) ^ ((col >> 1) & 3)) * 8;
            bf16x8 bL = *(const bf16x8*)(ts + col * 32 + swz);
            bf16x8 bH = *(const bf16x8*)(ts + (col + 32) * 32 + swz);
            accL = MFMA32(fr.v, bL, accL);
            accH = MFMA32(fr.v, bH, accH);
        }
    }

    // ---------------- epilogue: combine paths, normalize G2, store OutP
    __syncthreads();
    float* red  = (float*)smem;                // [128][68]
    float* Ltmp = (float*)(smem + 34816);      // [128] = 1/Lm

    if (wj == 1) {
        Lp += __shfl_xor(Lp, 32);
        if (l5 == 0) Ltmp[wm * 32 + col] = 1.0f / Lp;
    } else {
        #pragma unroll
        for (int r = 0; r < 16; ++r) {
            int m = wm * 32 + (r & 3) + 8 * (r >> 2) + 4 * l5;
            red[m * 68 + col]      = accL[r];
            red[m * 68 + 32 + col] = accH[r];
        }
    }
    __syncthreads();
    if (wj == 1) {
        #pragma unroll
        for (int r = 0; r < 16; ++r) {
            int ml = wm * 32 + (r & 3) + 8 * (r >> 2) + 4 * l5;
            float li = Ltmp[ml];
            red[ml * 68 + col]      += li * accL[r];
            red[ml * 68 + 32 + col] += li * accH[r];
        }
    }
    __syncthreads();
    {
        const int m  = tid >> 2;
        const int c0 = (tid & 3) * 16;
        const float* rp = red + m * 68 + c0;
        uint4 p0, p1;
        p0.x = pack_trunc(rp[0],  rp[1]);  p0.y = pack_trunc(rp[2],  rp[3]);
        p0.z = pack_trunc(rp[4],  rp[5]);  p0.w = pack_trunc(rp[6],  rp[7]);
        p1.x = pack_trunc(rp[8],  rp[9]);  p1.y = pack_trunc(rp[10], rp[11]);
        p1.z = pack_trunc(rp[12], rp[13]); p1.w = pack_trunc(rp[14], rp[15]);
        short* orow = OutPb + (size_t)(mt * 128 + m) * 64 + c0;
        *(uint4*)orow       = p0;
        *(uint4*)(orow + 8) = p1;
    }
}

// --------------------------------------------------------------- k_conv_out
__global__ __launch_bounds__(64) void k_conv_out(
    const char* __restrict__ ws,
    const float* __restrict__ Wo, const float* __restrict__ bo,
    float* __restrict__ out)
{
    const int lane = threadIdx.x;
    const int br   = blockIdx.x & 7;
    const int nt   = blockIdx.x >> 3;          // 0..127
    const int col  = lane & 31;
    const int l5   = lane >> 5;

    const short* OutPb = (const short*)(ws + OUTP_OFF) + (size_t)br * REG_ELEMS;

    bf16x8 afr[4];
    const short* arow = OutPb + (size_t)(nt * 32 + col) * 64 + l5 * 8;
    #pragma unroll
    for (int s = 0; s < 4; ++s) afr[s] = *(const bf16x8*)(arow + s * 16);

    bf16x8 bw[2][4];
    #pragma unroll
    for (int oh = 0; oh < 2; ++oh) {
        const float* wrow = Wo + (size_t)(oh * 32 + col) * 64 + l5 * 8;
        #pragma unroll
        for (int s = 0; s < 4; ++s) {
            float4 f0 = *(const float4*)(wrow + s * 16);
            float4 f1 = *(const float4*)(wrow + s * 16 + 4);
            union { bf16x8 v; short sh[8]; } u;
            u.sh[0] = f2bf(f0.x); u.sh[1] = f2bf(f0.y);
            u.sh[2] = f2bf(f0.z); u.sh[3] = f2bf(f0.w);
            u.sh[4] = f2bf(f1.x); u.sh[5] = f2bf(f1.y);
            u.sh[6] = f2bf(f1.z); u.sh[7] = f2bf(f1.w);
            bw[oh][s] = u.v;
        }
    }

    f32x16 d0 = zero16(), d1 = zero16();
    #pragma unroll
    for (int s = 0; s < 4; ++s) {
        d0 = MFMA32(afr[s], bw[0][s], d0);
        d1 = MFMA32(afr[s], bw[1][s], d1);
    }

    const int b  = br >> 2;
    const int gi = (br >> 1) & 1;
    const int gj = br & 1;

    #pragma unroll
    for (int oh = 0; oh < 2; ++oh) {
        const int oc = oh * 32 + col;
        const float bias = bo[oc];
        const f32x16& d = oh ? d1 : d0;
        #pragma unroll
        for (int q = 0; q < 4; ++q) {
            int nloc = 8 * q + 4 * l5;
            int nreg = nt * 32 + nloc;
            int wp   = nreg & 63;
            int ip   = nreg >> 6;
            float4 v = make_float4(d[4*q+0] + bias, d[4*q+1] + bias,
                                   d[4*q+2] + bias, d[4*q+3] + bias);
            float* op = out + ((size_t)(b * 64 + oc)) * 16384
                        + (size_t)(gi * 64 + ip) * 128 + gj * 64 + wp;
            *(float4*)op = v;
        }
    }
}

// -------------------------------------------------------------------- launch
extern "C" void kernel_launch(void* const* d_in, const int* in_sizes, int n_in,
                              void* d_out, int out_size, void* d_ws, size_t ws_size,
                              hipStream_t stream)
{
    const float* x  = (const float*)d_in[0];
    const float* Wq = (const float*)d_in[1];
    const float* bq = (const float*)d_in[2];
    const float* Wk = (const float*)d_in[3];
    const float* bk = (const float*)d_in[4];
    const float* Wa = (const float*)d_in[5];
    const float* ba = (const float*)d_in[6];
    const float* Wb = (const float*)d_in[7];
    const float* bb = (const float*)d_in[8];
    const float* Wo = (const float*)d_in[9];
    const float* bo = (const float*)d_in[10];
    char* ws   = (char*)d_ws;
    float* out = (float*)d_out;

    hipLaunchKernelGGL(k_conv_in,  dim3(512),  dim3(256), 0, stream,
                       x, Wq, bq, Wk, bk, Wa, ba, Wb, bb, ws);
    hipLaunchKernelGGL(k_stats,    dim3(256),  dim3(512), 0, stream, ws);
    hipLaunchKernelGGL(k_attn,     dim3(256),  dim3(512), 0, stream, ws);
    hipLaunchKernelGGL(k_conv_out, dim3(1024), dim3(64),  0, stream,
                       ws, Wo, bo, out);
}

// Round 5
// 231.952 us; speedup vs baseline: 6.1117x; 1.2006x over previous
//
#include <hip/hip_runtime.h>

// RegionSeparatedAttention on MI355X — round 5: 2 blocks/CU (m=64, 256 thr),
// native v_exp_f32, permlane32_swap weight transpose, Linv from stats.
//
// Global layouts in ws (per region br = b*4 + gi*2 + gj), ALL pre-swizzled:
//   Qp,Kp : bf16 [8][4096 n][64 c] pixel-major rows, seg' = seg ^ (n & 7)
//           (Q pre-scaled by 0.125*log2e)
//   Atl,Btl: bf16 [8][128 jtile][64 c][32 j], seg' = seg ^ ((c>>1) & 3)
//           (A gets *= Linv[j] in k_stats)
//   Linv  : f32 [8][4096]  (1 / softmax row sum, from k_stats)
//   OutP  : bf16 [8][4096 n][64 c] pixel-major, UNswizzled
//
// k_attn block = (br, mt of 64 m): 4 waves = (wm 0..1) x (wj path 0..1).
//   wj=0: d1[j][m]=S'[j][m], W=2^d1, acc += W x A'^T  (Linv[j] folded in A')
//   wj=1: d2[j][m]=S'[m][j], W=2^d2 raw, acc scaled by Linv[m] at epilogue.
// Slab = 32 j (16 KB Q/K/A/B), wave w stages tensor w, dbuf, 1 barrier/slab.

typedef __attribute__((ext_vector_type(8)))  short bf16x8;
typedef __attribute__((ext_vector_type(16))) float f32x16;

#define MFMA32(a, b, c) __builtin_amdgcn_mfma_f32_32x32x16_bf16(a, b, c, 0, 0, 0)

constexpr int REG_ELEMS = 4096 * 64;
constexpr size_t QP_OFF  = 0;
constexpr size_t KP_OFF  = 4u  << 20;
constexpr size_t ATL_OFF = 8u  << 20;
constexpr size_t BTL_OFF = 12u << 20;
constexpr size_t OUTP_OFF= 16u << 20;
constexpr size_t LNV_OFF = 20u << 20;      // f32 [8][4096]

constexpr float QSCALE = 0.18033688011112042f;  // 0.125 * log2(e)

__device__ __forceinline__ short f2bf(float f) {   // RNE
    union { float f; unsigned u; } v; v.f = f;
    unsigned r = v.u + 0x7fffu + ((v.u >> 16) & 1u);
    return (short)(r >> 16);
}
__device__ __forceinline__ float bf2f(short s) {
    union { unsigned u; float f; } v; v.u = ((unsigned)(unsigned short)s) << 16;
    return v.f;
}
__device__ __forceinline__ unsigned fbits(float f) {
    union { float f; unsigned u; } v; v.f = f; return v.u;
}
__device__ __forceinline__ unsigned pack_trunc(float e0, float e1) {
    return __builtin_amdgcn_perm(fbits(e1), fbits(e0), 0x07060302u);
}
__device__ __forceinline__ f32x16 zero16() {
    f32x16 z;
    #pragma unroll
    for (int i = 0; i < 16; ++i) z[i] = 0.f;
    return z;
}
__device__ __forceinline__ float fexp2(float x) {
#if __has_builtin(__builtin_amdgcn_exp2f)
    return __builtin_amdgcn_exp2f(x);
#else
    return exp2f(x);
#endif
}
// cross-half swap: a' = [lo: a_lo | hi: b_lo], b' = [lo: a_hi | hi: b_hi]
__device__ __forceinline__ void permswap32(unsigned& a, unsigned& b, bool hi) {
#if __has_builtin(__builtin_amdgcn_permlane32_swap)
    auto r = __builtin_amdgcn_permlane32_swap(a, b, false, false);
    a = r[0]; b = r[1];
#elif __has_builtin(__builtin_amdgcn_permlane32_swap_b32)
    auto r = __builtin_amdgcn_permlane32_swap_b32(a, b, false, false);
    a = r[0]; b = r[1];
#else
    unsigned ax = (unsigned)__shfl_xor((int)a, 32);
    unsigned bx = (unsigned)__shfl_xor((int)b, 32);
    unsigned na = hi ? bx : a;
    unsigned nb = hi ? b  : ax;
    a = na; b = nb;
#endif
}

typedef __attribute__((address_space(1))) const unsigned char as1_t;
typedef __attribute__((address_space(3))) unsigned char as3_t;
__device__ __forceinline__ void stage16(const void* g, void* l) {
    __builtin_amdgcn_global_load_lds((as1_t*)g, (as3_t*)l, 16, 0, 0);
}

// ---------------------------------------------------------------- k_conv_in
__global__ __launch_bounds__(256) void k_conv_in(
    const float* __restrict__ x,
    const float* __restrict__ Wq, const float* __restrict__ bq,
    const float* __restrict__ Wk, const float* __restrict__ bk,
    const float* __restrict__ Wa, const float* __restrict__ ba,
    const float* __restrict__ Wb, const float* __restrict__ bb,
    char* __restrict__ ws)
{
    const int tid  = threadIdx.x;
    const int blk  = blockIdx.x;
    const int wseg = blk & 1;
    const int h    = (blk >> 1) & 127;
    const int b    = blk >> 8;
    const int br   = b * 4 + (h >> 6) * 2 + wseg;
    const int n0   = (h & 63) * 64;

    __shared__ float xs[64][68];
    __shared__ short trans[2][64][72];

    const float* xp = x + ((size_t)b * 64 * 16384) + (size_t)h * 128 + wseg * 64;
    #pragma unroll
    for (int r = 0; r < 4; ++r) {
        int idx = r * 256 + tid;
        int c   = idx >> 4;
        int w4  = (idx & 15) << 2;
        *(float4*)&xs[c][w4] = *(const float4*)(xp + (size_t)c * 16384 + w4);
    }
    __syncthreads();

    const int mat = tid >> 6;
    const int oc  = tid & 63;
    const float* Wsel = (mat == 0) ? Wq : (mat == 1) ? Wk : (mat == 2) ? Wa : Wb;
    const float* bsel = (mat == 0) ? bq : (mat == 1) ? bk : (mat == 2) ? ba : bb;

    float acc[64];
    const float bias = bsel[oc];
    #pragma unroll
    for (int w = 0; w < 64; ++w) acc[w] = bias;

    #pragma unroll 8
    for (int c = 0; c < 64; ++c) {
        const float wv = Wsel[oc * 64 + c];
        #pragma unroll
        for (int w = 0; w < 64; ++w) acc[w] = fmaf(wv, xs[c][w], acc[w]);
    }

    if (mat == 0) {
        #pragma unroll
        for (int w = 0; w < 64; ++w) acc[w] *= QSCALE;
    }

    if (mat >= 2) {
        short tmp[64];
        #pragma unroll
        for (int w = 0; w < 64; ++w) tmp[w] = f2bf(acc[w]);
        short* base = (short*)(ws + (mat == 2 ? ATL_OFF : BTL_OFF))
                      + (size_t)br * REG_ELEMS;
        const int sw = (oc >> 1) & 3;
        #pragma unroll
        for (int w8 = 0; w8 < 8; ++w8) {
            int tile = (n0 >> 5) + (w8 >> 2);
            int segp = (w8 & 3) ^ sw;
            *(uint4*)(base + (size_t)tile * 2048 + oc * 32 + segp * 8) =
                *(uint4*)&tmp[w8 * 8];
        }
    } else {
        #pragma unroll
        for (int w = 0; w < 64; ++w) trans[mat][w][oc] = f2bf(acc[w]);
    }
    __syncthreads();

    #pragma unroll
    for (int rep = 0; rep < 4; ++rep) {
        int idx  = rep * 256 + tid;
        int mat2 = idx >> 9;
        int row  = (idx >> 3) & 63;
        int seg  = idx & 7;
        short* dst = (short*)(ws + (mat2 ? KP_OFF : QP_OFF))
                     + (size_t)br * REG_ELEMS + (size_t)(n0 + row) * 64
                     + (seg ^ (row & 7)) * 8;
        *(uint4*)dst = *(uint4*)&trans[mat2][row][seg * 8];
    }
}

// ------------------------------------------------------------------ k_stats
// block = (br, nt of 64 n-rows); 4 waves = (wn 0..1) x (wi m-half 0..1).
// L[n] = sum_m 2^S'[n][m]; Linv -> ws; A-tiles of this j-range *= Linv.
__global__ __launch_bounds__(256, 2) void k_stats(char* __restrict__ ws)
{
    const int tid  = threadIdx.x;
    const int br   = blockIdx.x & 7;
    const int nt   = blockIdx.x >> 3;          // 0..63
    const int lane = tid & 63;
    const int w    = tid >> 6;
    const int wn   = w & 1;
    const int wi   = w >> 1;
    const int col  = lane & 31;
    const int l5   = lane >> 5;

    const short* Qb  = (const short*)(ws + QP_OFF) + (size_t)br * REG_ELEMS;
    const char*  Kbb = ws + KP_OFF + (size_t)br * REG_ELEMS * 2;

    __shared__ __align__(16) char smem[17408];  // dbuf 16K | Lred 512 | Larr 256

    const int nrow = nt * 64 + wn * 32 + col;
    bf16x8 afr[4];
    #pragma unroll
    for (int s = 0; s < 4; ++s)
        afr[s] = *(const bf16x8*)(Qb + (size_t)nrow * 64 + (((2*s+l5) ^ (col & 7)) * 8));

    float sm[16];
    #pragma unroll
    for (int r = 0; r < 16; ++r) sm[r] = 0.f;

    {   // stage slab 0 (64 m-rows = 8 KB; wave w covers 2 KB)
        const char* g = Kbb + (size_t)w * 2048 + lane * 16;
        char* l = smem + w * 2048;
        stage16(g, l); stage16(g + 1024, l + 1024);
    }

    #pragma unroll 2
    for (int slab = 0; slab < 64; ++slab) {
        __syncthreads();
        if (slab + 1 < 64) {
            const char* g = Kbb + (size_t)(slab + 1) * 8192 + w * 2048 + lane * 16;
            char* l = smem + ((slab + 1) & 1) * 8192 + w * 2048;
            stage16(g, l); stage16(g + 1024, l + 1024);
        }
        const short* Ks = (const short*)(smem + (slab & 1) * 8192);
        f32x16 d = zero16();
        #pragma unroll
        for (int s = 0; s < 4; ++s) {
            bf16x8 bf = *(const bf16x8*)(Ks + (wi * 32 + col) * 64
                                         + ((2*s+l5) ^ (col & 7)) * 8);
            d = MFMA32(afr[s], bf, d);
        }
        #pragma unroll
        for (int r = 0; r < 16; ++r) sm[r] += fexp2(d[r]);
    }

    #pragma unroll
    for (int off = 1; off < 32; off <<= 1)
        #pragma unroll
        for (int r = 0; r < 16; ++r) sm[r] += __shfl_xor(sm[r], off);

    __syncthreads();
    float* Lred = (float*)(smem + 16384);      // [4][32]
    float* Larr = (float*)(smem + 16896);      // [64] = 1/L
    if (col == 0) {
        #pragma unroll
        for (int r = 0; r < 16; ++r)
            Lred[w * 32 + ((r & 3) + 8 * (r >> 2) + 4 * l5)] = sm[r];
    }
    __syncthreads();
    if (tid < 64) {
        int wn2 = tid >> 5, nl = tid & 31;
        float L = Lred[wn2 * 32 + nl] + Lred[(wn2 + 2) * 32 + nl];
        float li = 1.0f / L;
        Larr[tid] = li;
        ((float*)(ws + LNV_OFF))[(size_t)br * 4096 + nt * 64 + tid] = li;
    }
    __syncthreads();

    // scale A-tiles of this j-range (tiles 2nt, 2nt+1), swizzle-aware
    short* Ab = (short*)(ws + ATL_OFF) + (size_t)br * REG_ELEMS + (size_t)nt * 4096;
    #pragma unroll
    for (int rep = 0; rep < 2; ++rep) {
        int id = rep * 256 + tid;              // 0..511 chunks of 16B
        int t = id >> 8, c = (id >> 2) & 63, s = id & 3;
        int sg = s ^ ((c >> 1) & 3);
        int jl = t * 32 + sg * 8;
        short* p = Ab + (size_t)t * 2048 + c * 32 + s * 8;
        uint4 v = *(uint4*)p;
        short* sp = (short*)&v;
        short o[8];
        #pragma unroll
        for (int e = 0; e < 8; ++e) o[e] = f2bf(bf2f(sp[e]) * Larr[jl + e]);
        *(uint4*)p = *(uint4*)o;
    }
}

// ------------------------------------------------------------------- k_attn
__global__ __launch_bounds__(256, 2) void k_attn(char* __restrict__ ws)
{
    const int tid  = threadIdx.x;
    const int br   = blockIdx.x & 7;
    const int mt   = blockIdx.x >> 3;          // 0..63, m-tile of 64
    const int lane = tid & 63;
    const int w    = tid >> 6;
    const int wm   = w & 1;                    // m-sub-32
    const int wj   = w >> 1;                   // path: 0 = G1*A', 1 = G2*B
    const int col  = lane & 31;
    const int l5   = lane >> 5;
    const bool hi  = (l5 != 0);

    const char* Qbb = ws + QP_OFF  + (size_t)br * REG_ELEMS * 2;
    const char* Kbb = ws + KP_OFF  + (size_t)br * REG_ELEMS * 2;
    const char* Abb = ws + ATL_OFF + (size_t)br * REG_ELEMS * 2;
    const char* Bbb = ws + BTL_OFF + (size_t)br * REG_ELEMS * 2;
    const float* Lnv = (const float*)(ws + LNV_OFF) + (size_t)br * 4096;
    short* OutPb    = (short*)(ws + OUTP_OFF) + (size_t)br * REG_ELEMS;

    __shared__ __align__(16) char smem[32768];  // dbuf 2x16K; epilogue red overlay

    const int mrow = mt * 64 + wm * 32 + col;
    const short* msrc = (const short*)(wj == 0 ? Kbb : Qbb) + (size_t)mrow * 64;
    bf16x8 mf[4];
    #pragma unroll
    for (int s = 0; s < 4; ++s)
        mf[s] = *(const bf16x8*)(msrc + ((2*s+l5) ^ (col & 7)) * 8);

    f32x16 accL = zero16(), accH = zero16();

    // wave w stages tensor w (Q|K|A|B), 4 KB = 4 instr
    const char* gsb = (w == 0) ? Qbb : (w == 1) ? Kbb : (w == 2) ? Abb : Bbb;

    {   // stage slab 0
        const char* g = gsb + lane * 16;
        char* l = smem + w * 4096 + lane * 16;
        #pragma unroll
        for (int i = 0; i < 4; ++i) stage16(g + i * 1024, l + i * 1024);
    }

    #pragma unroll 2
    for (int slab = 0; slab < 128; ++slab) {
        __syncthreads();
        if (slab + 1 < 128) {
            const char* g = gsb + (size_t)(slab + 1) * 4096 + lane * 16;
            char* l = smem + ((slab + 1) & 1) * 16384 + w * 4096 + lane * 16;
            #pragma unroll
            for (int i = 0; i < 4; ++i) stage16(g + i * 1024, l + i * 1024);
        }
        const char* sb = smem + (slab & 1) * 16384;
        const short* js = (const short*)(sb + (wj == 0 ? 0 : 4096));      // Q | K rows
        const short* ts = (const short*)(sb + (wj == 0 ? 8192 : 12288));  // A' | B tile

        // S-MFMA: d[j][m]
        f32x16 d = zero16();
        #pragma unroll
        for (int s = 0; s < 4; ++s) {
            bf16x8 a = *(const bf16x8*)(js + col * 64 + ((2*s+l5) ^ (col & 7)) * 8);
            d = MFMA32(a, mf[s], d);
        }

        // raw exp2 weights (normalizers folded in A' / deferred via Linv[m])
        unsigned Wp[8];
        #pragma unroll
        for (int q = 0; q < 4; ++q) {
            Wp[2*q]   = pack_trunc(fexp2(d[4*q]),   fexp2(d[4*q+1]));
            Wp[2*q+1] = pack_trunc(fexp2(d[4*q+2]), fexp2(d[4*q+3]));
        }

        // C-layout -> A-operand transpose via permlane32_swap, then out-MFMAs
        #pragma unroll
        for (int k16 = 0; k16 < 2; ++k16) {
            unsigned u0 = Wp[4*k16+0], u1 = Wp[4*k16+1];
            unsigned u2 = Wp[4*k16+2], u3 = Wp[4*k16+3];
            permswap32(u0, u2, hi);
            permswap32(u1, u3, hi);
            union { uint4 u; bf16x8 v; } fr;
            fr.u.x = u0; fr.u.y = u1; fr.u.z = u2; fr.u.w = u3;

            const int swz = ((2*k16 + l5) ^ ((col >> 1) & 3)) * 8;
            bf16x8 bL = *(const bf16x8*)(ts + col * 32 + swz);
            bf16x8 bH = *(const bf16x8*)(ts + (col + 32) * 32 + swz);
            accL = MFMA32(fr.v, bL, accL);
            accH = MFMA32(fr.v, bH, accH);
        }
    }

    // epilogue: path-0 writes, path-1 adds (scaled by Linv[m]), pack + store
    __syncthreads();
    float* red = (float*)smem;                 // [64][68]
    if (wj == 0) {
        #pragma unroll
        for (int r = 0; r < 16; ++r) {
            int ml = wm * 32 + (r & 3) + 8 * (r >> 2) + 4 * l5;
            red[ml * 68 + col]      = accL[r];
            red[ml * 68 + 32 + col] = accH[r];
        }
    }
    __syncthreads();
    if (wj == 1) {
        #pragma unroll
        for (int r = 0; r < 16; ++r) {
            int ml = wm * 32 + (r & 3) + 8 * (r >> 2) + 4 * l5;
            float li = Lnv[mt * 64 + ml];
            red[ml * 68 + col]      += li * accL[r];
            red[ml * 68 + 32 + col] += li * accH[r];
        }
    }
    __syncthreads();
    {
        const int m  = tid >> 2;
        const int c0 = (tid & 3) * 16;
        const float* rp = red + m * 68 + c0;
        uint4 p0, p1;
        p0.x = pack_trunc(rp[0],  rp[1]);  p0.y = pack_trunc(rp[2],  rp[3]);
        p0.z = pack_trunc(rp[4],  rp[5]);  p0.w = pack_trunc(rp[6],  rp[7]);
        p1.x = pack_trunc(rp[8],  rp[9]);  p1.y = pack_trunc(rp[10], rp[11]);
        p1.z = pack_trunc(rp[12], rp[13]); p1.w = pack_trunc(rp[14], rp[15]);
        short* orow = OutPb + (size_t)(mt * 64 + m) * 64 + c0;
        *(uint4*)orow       = p0;
        *(uint4*)(orow + 8) = p1;
    }
}

// --------------------------------------------------------------- k_conv_out
__global__ __launch_bounds__(64) void k_conv_out(
    const char* __restrict__ ws,
    const float* __restrict__ Wo, const float* __restrict__ bo,
    float* __restrict__ out)
{
    const int lane = threadIdx.x;
    const int br   = blockIdx.x & 7;
    const int nt   = blockIdx.x >> 3;          // 0..127
    const int col  = lane & 31;
    const int l5   = lane >> 5;

    const short* OutPb = (const short*)(ws + OUTP_OFF) + (size_t)br * REG_ELEMS;

    bf16x8 afr[4];
    const short* arow = OutPb + (size_t)(nt * 32 + col) * 64 + l5 * 8;
    #pragma unroll
    for (int s = 0; s < 4; ++s) afr[s] = *(const bf16x8*)(arow + s * 16);

    bf16x8 bw[2][4];
    #pragma unroll
    for (int oh = 0; oh < 2; ++oh) {
        const float* wrow = Wo + (size_t)(oh * 32 + col) * 64 + l5 * 8;
        #pragma unroll
        for (int s = 0; s < 4; ++s) {
            float4 f0 = *(const float4*)(wrow + s * 16);
            float4 f1 = *(const float4*)(wrow + s * 16 + 4);
            union { bf16x8 v; short sh[8]; } u;
            u.sh[0] = f2bf(f0.x); u.sh[1] = f2bf(f0.y);
            u.sh[2] = f2bf(f0.z); u.sh[3] = f2bf(f0.w);
            u.sh[4] = f2bf(f1.x); u.sh[5] = f2bf(f1.y);
            u.sh[6] = f2bf(f1.z); u.sh[7] = f2bf(f1.w);
            bw[oh][s] = u.v;
        }
    }

    f32x16 d0 = zero16(), d1 = zero16();
    #pragma unroll
    for (int s = 0; s < 4; ++s) {
        d0 = MFMA32(afr[s], bw[0][s], d0);
        d1 = MFMA32(afr[s], bw[1][s], d1);
    }

    const int b  = br >> 2;
    const int gi = (br >> 1) & 1;
    const int gj = br & 1;

    #pragma unroll
    for (int oh = 0; oh < 2; ++oh) {
        const int oc = oh * 32 + col;
        const float bias = bo[oc];
        const f32x16& d = oh ? d1 : d0;
        #pragma unroll
        for (int q = 0; q < 4; ++q) {
            int nloc = 8 * q + 4 * l5;
            int nreg = nt * 32 + nloc;
            int wp   = nreg & 63;
            int ip   = nreg >> 6;
            float4 v = make_float4(d[4*q+0] + bias, d[4*q+1] + bias,
                                   d[4*q+2] + bias, d[4*q+3] + bias);
            float* op = out + ((size_t)(b * 64 + oc)) * 16384
                        + (size_t)(gi * 64 + ip) * 128 + gj * 64 + wp;
            *(float4*)op = v;
        }
    }
}

// -------------------------------------------------------------------- launch
extern "C" void kernel_launch(void* const* d_in, const int* in_sizes, int n_in,
                              void* d_out, int out_size, void* d_ws, size_t ws_size,
                              hipStream_t stream)
{
    const float* x  = (const float*)d_in[0];
    const float* Wq = (const float*)d_in[1];
    const float* bq = (const float*)d_in[2];
    const float* Wk = (const float*)d_in[3];
    const float* bk = (const float*)d_in[4];
    const float* Wa = (const float*)d_in[5];
    const float* ba = (const float*)d_in[6];
    const float* Wb = (const float*)d_in[7];
    const float* bb = (const float*)d_in[8];
    const float* Wo = (const float*)d_in[9];
    const float* bo = (const float*)d_in[10];
    char* ws   = (char*)d_ws;
    float* out = (float*)d_out;

    hipLaunchKernelGGL(k_conv_in,  dim3(512),  dim3(256), 0, stream,
                       x, Wq, bq, Wk, bk, Wa, ba, Wb, bb, ws);
    hipLaunchKernelGGL(k_stats,    dim3(512),  dim3(256), 0, stream, ws);
    hipLaunchKernelGGL(k_attn,     dim3(512),  dim3(256), 0, stream, ws);
    hipLaunchKernelGGL(k_conv_out, dim3(1024), dim3(64),  0, stream,
                       ws, Wo, bo, out);
}

// Round 8
// 206.126 us; speedup vs baseline: 6.8775x; 1.1253x over previous
//
#include <hip/hip_runtime.h>

// RegionSeparatedAttention on MI355X — round 8: FULL revert to round-5 green
// (k_stats / k_attn / k_conv_out verbatim), plus k_conv_in rewritten as MFMA
// (x,W hi+lo bf16 split => fp32-accurate) keeping output layouts/stores
// byte-identical.  Fused-conv epilogue abandoned (2 red rounds, audit-clean
// but failing — see journal).
//
// Global layouts in ws (per region br = b*4 + gi*2 + gj), ALL pre-swizzled:
//   Qp,Kp : bf16 [8][4096 n][64 c] pixel-major rows, seg' = seg ^ (n & 7)
//           (Q pre-scaled by 0.125*log2e)
//   Atl,Btl: bf16 [8][128 jtile][64 c][32 j], seg' = seg ^ ((c>>1) & 3)
//           (A gets *= Linv[j] in k_stats)
//   OutP  : bf16 [8][4096 n][64 c] pixel-major, UNswizzled
//   Linv  : f32 [8][4096]  (1 / softmax row sum, from k_stats)

typedef __attribute__((ext_vector_type(8)))  short bf16x8;
typedef __attribute__((ext_vector_type(16))) float f32x16;

#define MFMA32(a, b, c) __builtin_amdgcn_mfma_f32_32x32x16_bf16(a, b, c, 0, 0, 0)

constexpr int REG_ELEMS = 4096 * 64;
constexpr size_t QP_OFF  = 0;
constexpr size_t KP_OFF  = 4u  << 20;
constexpr size_t ATL_OFF = 8u  << 20;
constexpr size_t BTL_OFF = 12u << 20;
constexpr size_t OUTP_OFF= 16u << 20;
constexpr size_t LNV_OFF = 20u << 20;      // f32 [8][4096]

constexpr float QSCALE = 0.18033688011112042f;  // 0.125 * log2(e)

__device__ __forceinline__ short f2bf(float f) {   // RNE
    union { float f; unsigned u; } v; v.f = f;
    unsigned r = v.u + 0x7fffu + ((v.u >> 16) & 1u);
    return (short)(r >> 16);
}
__device__ __forceinline__ float bf2f(short s) {
    union { unsigned u; float f; } v; v.u = ((unsigned)(unsigned short)s) << 16;
    return v.f;
}
__device__ __forceinline__ unsigned fbits(float f) {
    union { float f; unsigned u; } v; v.f = f; return v.u;
}
__device__ __forceinline__ unsigned pack_trunc(float e0, float e1) {
    return __builtin_amdgcn_perm(fbits(e1), fbits(e0), 0x07060302u);
}
__device__ __forceinline__ f32x16 zero16() {
    f32x16 z;
    #pragma unroll
    for (int i = 0; i < 16; ++i) z[i] = 0.f;
    return z;
}
__device__ __forceinline__ float fexp2(float x) {
#if __has_builtin(__builtin_amdgcn_exp2f)
    return __builtin_amdgcn_exp2f(x);
#else
    return exp2f(x);
#endif
}
__device__ __forceinline__ void permswap32(unsigned& a, unsigned& b, bool hi) {
#if __has_builtin(__builtin_amdgcn_permlane32_swap)
    auto r = __builtin_amdgcn_permlane32_swap(a, b, false, false);
    a = r[0]; b = r[1];
#elif __has_builtin(__builtin_amdgcn_permlane32_swap_b32)
    auto r = __builtin_amdgcn_permlane32_swap_b32(a, b, false, false);
    a = r[0]; b = r[1];
#else
    unsigned ax = (unsigned)__shfl_xor((int)a, 32);
    unsigned bx = (unsigned)__shfl_xor((int)b, 32);
    unsigned na = hi ? bx : a;
    unsigned nb = hi ? b  : ax;
    a = na; b = nb;
#endif
}

typedef __attribute__((address_space(1))) const unsigned char as1_t;
typedef __attribute__((address_space(3))) unsigned char as3_t;
__device__ __forceinline__ void stage16(const void* g, void* l) {
    __builtin_amdgcn_global_load_lds((as1_t*)g, (as3_t*)l, 16, 0, 0);
}

// ---------------------------------------------------------------- k_conv_in
// MFMA rewrite: block = (b, h, wseg) covers 64 px x 64 c.  4 waves =
// (pH pixel-half) x (oH oc-half); each wave does its quadrant of all 4
// matrices.  x and W split hi+lo bf16; D = hi*hi + hi*lo + lo*hi (~fp32).
// Output stores byte-identical to round-5 layouts.
__global__ __launch_bounds__(256) void k_conv_in(
    const float* __restrict__ x,
    const float* __restrict__ Wq, const float* __restrict__ bq,
    const float* __restrict__ Wk, const float* __restrict__ bk,
    const float* __restrict__ Wa, const float* __restrict__ ba,
    const float* __restrict__ Wb, const float* __restrict__ bb,
    char* __restrict__ ws)
{
    const int tid  = threadIdx.x;
    const int blk  = blockIdx.x;
    const int wseg = blk & 1;
    const int h    = (blk >> 1) & 127;
    const int b    = blk >> 8;
    const int br   = b * 4 + (h >> 6) * 2 + wseg;
    const int n0   = (h & 63) * 64;

    __shared__ float xs[64][68];               // [c][px]
    __shared__ short trans[2][64][72];         // [mat][px][oc]

    const float* xp = x + ((size_t)b * 64 * 16384) + (size_t)h * 128 + wseg * 64;
    #pragma unroll
    for (int r = 0; r < 4; ++r) {
        int idx = r * 256 + tid;
        int c   = idx >> 4;
        int w4  = (idx & 15) << 2;
        *(float4*)&xs[c][w4] = *(const float4*)(xp + (size_t)c * 16384 + w4);
    }
    __syncthreads();

    const int lane = tid & 63;
    const int wid  = tid >> 6;
    const int col  = lane & 31;
    const int l5   = lane >> 5;
    const int pH   = wid & 1;                  // pixel half
    const int oH   = wid >> 1;                 // oc half
    const int px   = pH * 32 + col;
    const int oc   = oH * 32 + col;

    // A-frags: x^T[px][k=c], hi+lo split
    bf16x8 xhi[4], xlo[4];
    #pragma unroll
    for (int s = 0; s < 4; ++s) {
        union { bf16x8 v; short sh[8]; } uh, ul;
        #pragma unroll
        for (int e = 0; e < 8; ++e) {
            float xv = xs[s * 16 + l5 * 8 + e][px];
            short hh = f2bf(xv);
            uh.sh[e] = hh;
            ul.sh[e] = f2bf(xv - bf2f(hh));
        }
        xhi[s] = uh.v; xlo[s] = ul.v;
    }

    #pragma unroll
    for (int mat = 0; mat < 4; ++mat) {
        const float* Wsel = (mat == 0) ? Wq : (mat == 1) ? Wk : (mat == 2) ? Wa : Wb;
        const float* bsel = (mat == 0) ? bq : (mat == 1) ? bk : (mat == 2) ? ba : bb;

        // B-frags: W[oc][k=c], hi+lo split
        bf16x8 whi[4], wlo[4];
        const float* wrow = Wsel + (size_t)oc * 64;
        #pragma unroll
        for (int s = 0; s < 4; ++s) {
            float4 f0 = *(const float4*)(wrow + s * 16 + l5 * 8);
            float4 f1 = *(const float4*)(wrow + s * 16 + l5 * 8 + 4);
            float wf[8] = { f0.x, f0.y, f0.z, f0.w, f1.x, f1.y, f1.z, f1.w };
            union { bf16x8 v; short sh[8]; } uh, ul;
            #pragma unroll
            for (int e = 0; e < 8; ++e) {
                short hh = f2bf(wf[e]);
                uh.sh[e] = hh;
                ul.sh[e] = f2bf(wf[e] - bf2f(hh));
            }
            whi[s] = uh.v; wlo[s] = ul.v;
        }

        f32x16 d = zero16();
        #pragma unroll
        for (int s = 0; s < 4; ++s) {
            d = MFMA32(xhi[s], whi[s], d);
            d = MFMA32(xhi[s], wlo[s], d);
            d = MFMA32(xlo[s], whi[s], d);
        }

        const float bias = bsel[oc];
        if (mat < 2) {
            // D[px][oc] -> trans[mat][px][oc] (Q scaled), bf16 RNE
            const float sc = (mat == 0) ? QSCALE : 1.0f;
            #pragma unroll
            for (int r = 0; r < 16; ++r) {
                int pxl = pH * 32 + (r & 3) + 8 * (r >> 2) + 4 * l5;
                trans[mat][pxl][oc] = f2bf((d[r] + bias) * sc);
            }
        } else {
            // direct tiled channel-major store (same addresses as round 5)
            short* base = (short*)(ws + (mat == 2 ? ATL_OFF : BTL_OFF))
                          + (size_t)br * REG_ELEMS;
            const int sw   = (oc >> 1) & 3;
            const int tile = (n0 >> 5) + pH;
            #pragma unroll
            for (int q = 0; q < 4; ++q) {
                short tmp4[4];
                #pragma unroll
                for (int rr = 0; rr < 4; ++rr) tmp4[rr] = f2bf(d[4 * q + rr] + bias);
                int segp = q ^ sw;
                short* p = base + (size_t)tile * 2048 + oc * 32 + segp * 8 + 4 * l5;
                *(uint2*)p = *(uint2*)tmp4;
            }
        }
    }
    __syncthreads();

    // cooperative pixel-major Q/K store with seg swizzle (round-5 verbatim)
    #pragma unroll
    for (int rep = 0; rep < 4; ++rep) {
        int idx  = rep * 256 + tid;
        int mat2 = idx >> 9;
        int row  = (idx >> 3) & 63;
        int seg  = idx & 7;
        short* dst = (short*)(ws + (mat2 ? KP_OFF : QP_OFF))
                     + (size_t)br * REG_ELEMS + (size_t)(n0 + row) * 64
                     + (seg ^ (row & 7)) * 8;
        *(uint4*)dst = *(uint4*)&trans[mat2][row][seg * 8];
    }
}

// ------------------------------------------------------------------ k_stats
// (round-5 verbatim)
__global__ __launch_bounds__(256, 2) void k_stats(char* __restrict__ ws)
{
    const int tid  = threadIdx.x;
    const int br   = blockIdx.x & 7;
    const int nt   = blockIdx.x >> 3;          // 0..63
    const int lane = tid & 63;
    const int w    = tid >> 6;
    const int wn   = w & 1;
    const int wi   = w >> 1;
    const int col  = lane & 31;
    const int l5   = lane >> 5;

    const short* Qb  = (const short*)(ws + QP_OFF) + (size_t)br * REG_ELEMS;
    const char*  Kbb = ws + KP_OFF + (size_t)br * REG_ELEMS * 2;

    __shared__ __align__(16) char smem[17408];  // dbuf 16K | Lred 512 | Larr 256

    const int nrow = nt * 64 + wn * 32 + col;
    bf16x8 afr[4];
    #pragma unroll
    for (int s = 0; s < 4; ++s)
        afr[s] = *(const bf16x8*)(Qb + (size_t)nrow * 64 + (((2*s+l5) ^ (col & 7)) * 8));

    float sm[16];
    #pragma unroll
    for (int r = 0; r < 16; ++r) sm[r] = 0.f;

    {   // stage slab 0 (64 m-rows = 8 KB; wave w covers 2 KB)
        const char* g = Kbb + (size_t)w * 2048 + lane * 16;
        char* l = smem + w * 2048;
        stage16(g, l); stage16(g + 1024, l + 1024);
    }

    #pragma unroll 2
    for (int slab = 0; slab < 64; ++slab) {
        __syncthreads();
        if (slab + 1 < 64) {
            const char* g = Kbb + (size_t)(slab + 1) * 8192 + w * 2048 + lane * 16;
            char* l = smem + ((slab + 1) & 1) * 8192 + w * 2048;
            stage16(g, l); stage16(g + 1024, l + 1024);
        }
        const short* Ks = (const short*)(smem + (slab & 1) * 8192);
        f32x16 d = zero16();
        #pragma unroll
        for (int s = 0; s < 4; ++s) {
            bf16x8 bf = *(const bf16x8*)(Ks + (wi * 32 + col) * 64
                                         + ((2*s+l5) ^ (col & 7)) * 8);
            d = MFMA32(afr[s], bf, d);
        }
        #pragma unroll
        for (int r = 0; r < 16; ++r) sm[r] += fexp2(d[r]);
    }

    #pragma unroll
    for (int off = 1; off < 32; off <<= 1)
        #pragma unroll
        for (int r = 0; r < 16; ++r) sm[r] += __shfl_xor(sm[r], off);

    __syncthreads();
    float* Lred = (float*)(smem + 16384);      // [4][32]
    float* Larr = (float*)(smem + 16896);      // [64] = 1/L
    if (col == 0) {
        #pragma unroll
        for (int r = 0; r < 16; ++r)
            Lred[w * 32 + ((r & 3) + 8 * (r >> 2) + 4 * l5)] = sm[r];
    }
    __syncthreads();
    if (tid < 64) {
        int wn2 = tid >> 5, nl = tid & 31;
        float L = Lred[wn2 * 32 + nl] + Lred[(wn2 + 2) * 32 + nl];
        float li = 1.0f / L;
        Larr[tid] = li;
        ((float*)(ws + LNV_OFF))[(size_t)br * 4096 + nt * 64 + tid] = li;
    }
    __syncthreads();

    // scale A-tiles of this j-range (tiles 2nt, 2nt+1), swizzle-aware
    short* Ab = (short*)(ws + ATL_OFF) + (size_t)br * REG_ELEMS + (size_t)nt * 4096;
    #pragma unroll
    for (int rep = 0; rep < 2; ++rep) {
        int id = rep * 256 + tid;              // 0..511 chunks of 16B
        int t = id >> 8, c = (id >> 2) & 63, s = id & 3;
        int sg = s ^ ((c >> 1) & 3);
        int jl = t * 32 + sg * 8;
        short* p = Ab + (size_t)t * 2048 + c * 32 + s * 8;
        uint4 v = *(uint4*)p;
        short* sp = (short*)&v;
        short o[8];
        #pragma unroll
        for (int e = 0; e < 8; ++e) o[e] = f2bf(bf2f(sp[e]) * Larr[jl + e]);
        *(uint4*)p = *(uint4*)o;
    }
}

// ------------------------------------------------------------------- k_attn
// (round-5 verbatim)
__global__ __launch_bounds__(256, 2) void k_attn(char* __restrict__ ws)
{
    const int tid  = threadIdx.x;
    const int br   = blockIdx.x & 7;
    const int mt   = blockIdx.x >> 3;          // 0..63, m-tile of 64
    const int lane = tid & 63;
    const int w    = tid >> 6;
    const int wm   = w & 1;                    // m-sub-32
    const int wj   = w >> 1;                   // path: 0 = G1*A', 1 = G2*B
    const int col  = lane & 31;
    const int l5   = lane >> 5;
    const bool hi  = (l5 != 0);

    const char* Qbb = ws + QP_OFF  + (size_t)br * REG_ELEMS * 2;
    const char* Kbb = ws + KP_OFF  + (size_t)br * REG_ELEMS * 2;
    const char* Abb = ws + ATL_OFF + (size_t)br * REG_ELEMS * 2;
    const char* Bbb = ws + BTL_OFF + (size_t)br * REG_ELEMS * 2;
    const float* Lnv = (const float*)(ws + LNV_OFF) + (size_t)br * 4096;
    short* OutPb    = (short*)(ws + OUTP_OFF) + (size_t)br * REG_ELEMS;

    __shared__ __align__(16) char smem[32768];  // dbuf 2x16K; epilogue red overlay

    const int mrow = mt * 64 + wm * 32 + col;
    const short* msrc = (const short*)(wj == 0 ? Kbb : Qbb) + (size_t)mrow * 64;
    bf16x8 mf[4];
    #pragma unroll
    for (int s = 0; s < 4; ++s)
        mf[s] = *(const bf16x8*)(msrc + ((2*s+l5) ^ (col & 7)) * 8);

    f32x16 accL = zero16(), accH = zero16();

    // wave w stages tensor w (Q|K|A|B), 4 KB = 4 instr
    const char* gsb = (w == 0) ? Qbb : (w == 1) ? Kbb : (w == 2) ? Abb : Bbb;

    {   // stage slab 0
        const char* g = gsb + lane * 16;
        char* l = smem + w * 4096 + lane * 16;
        #pragma unroll
        for (int i = 0; i < 4; ++i) stage16(g + i * 1024, l + i * 1024);
    }

    #pragma unroll 2
    for (int slab = 0; slab < 128; ++slab) {
        __syncthreads();
        if (slab + 1 < 128) {
            const char* g = gsb + (size_t)(slab + 1) * 4096 + lane * 16;
            char* l = smem + ((slab + 1) & 1) * 16384 + w * 4096 + lane * 16;
            #pragma unroll
            for (int i = 0; i < 4; ++i) stage16(g + i * 1024, l + i * 1024);
        }
        const char* sb = smem + (slab & 1) * 16384;
        const short* js = (const short*)(sb + (wj == 0 ? 0 : 4096));      // Q | K rows
        const short* ts = (const short*)(sb + (wj == 0 ? 8192 : 12288));  // A' | B tile

        // S-MFMA: d[j][m]
        f32x16 d = zero16();
        #pragma unroll
        for (int s = 0; s < 4; ++s) {
            bf16x8 a = *(const bf16x8*)(js + col * 64 + ((2*s+l5) ^ (col & 7)) * 8);
            d = MFMA32(a, mf[s], d);
        }

        // raw exp2 weights (normalizers folded in A' / deferred via Linv[m])
        unsigned Wp[8];
        #pragma unroll
        for (int q = 0; q < 4; ++q) {
            Wp[2*q]   = pack_trunc(fexp2(d[4*q]),   fexp2(d[4*q+1]));
            Wp[2*q+1] = pack_trunc(fexp2(d[4*q+2]), fexp2(d[4*q+3]));
        }

        // C-layout -> A-operand transpose via permlane32_swap, then out-MFMAs
        #pragma unroll
        for (int k16 = 0; k16 < 2; ++k16) {
            unsigned u0 = Wp[4*k16+0], u1 = Wp[4*k16+1];
            unsigned u2 = Wp[4*k16+2], u3 = Wp[4*k16+3];
            permswap32(u0, u2, hi);
            permswap32(u1, u3, hi);
            union { uint4 u; bf16x8 v; } fr;
            fr.u.x = u0; fr.u.y = u1; fr.u.z = u2; fr.u.w = u3;

            const int swz = ((2*k16 + l5) ^ ((col >> 1) & 3)) * 8;
            bf16x8 bL = *(const bf16x8*)(ts + col * 32 + swz);
            bf16x8 bH = *(const bf16x8*)(ts + (col + 32) * 32 + swz);
            accL = MFMA32(fr.v, bL, accL);
            accH = MFMA32(fr.v, bH, accH);
        }
    }

    // epilogue: path-0 writes, path-1 adds (scaled by Linv[m]), pack + store
    __syncthreads();
    float* red = (float*)smem;                 // [64][68]
    if (wj == 0) {
        #pragma unroll
        for (int r = 0; r < 16; ++r) {
            int ml = wm * 32 + (r & 3) + 8 * (r >> 2) + 4 * l5;
            red[ml * 68 + col]      = accL[r];
            red[ml * 68 + 32 + col] = accH[r];
        }
    }
    __syncthreads();
    if (wj == 1) {
        #pragma unroll
        for (int r = 0; r < 16; ++r) {
            int ml = wm * 32 + (r & 3) + 8 * (r >> 2) + 4 * l5;
            float li = Lnv[mt * 64 + ml];
            red[ml * 68 + col]      += li * accL[r];
            red[ml * 68 + 32 + col] += li * accH[r];
        }
    }
    __syncthreads();
    {
        const int m  = tid >> 2;
        const int c0 = (tid & 3) * 16;
        const float* rp = red + m * 68 + c0;
        uint4 p0, p1;
        p0.x = pack_trunc(rp[0],  rp[1]);  p0.y = pack_trunc(rp[2],  rp[3]);
        p0.z = pack_trunc(rp[4],  rp[5]);  p0.w = pack_trunc(rp[6],  rp[7]);
        p1.x = pack_trunc(rp[8],  rp[9]);  p1.y = pack_trunc(rp[10], rp[11]);
        p1.z = pack_trunc(rp[12], rp[13]); p1.w = pack_trunc(rp[14], rp[15]);
        short* orow = OutPb + (size_t)(mt * 64 + m) * 64 + c0;
        *(uint4*)orow       = p0;
        *(uint4*)(orow + 8) = p1;
    }
}

// --------------------------------------------------------------- k_conv_out
// (round-5 verbatim)
__global__ __launch_bounds__(64) void k_conv_out(
    const char* __restrict__ ws,
    const float* __restrict__ Wo, const float* __restrict__ bo,
    float* __restrict__ out)
{
    const int lane = threadIdx.x;
    const int br   = blockIdx.x & 7;
    const int nt   = blockIdx.x >> 3;          // 0..127
    const int col  = lane & 31;
    const int l5   = lane >> 5;

    const short* OutPb = (const short*)(ws + OUTP_OFF) + (size_t)br * REG_ELEMS;

    bf16x8 afr[4];
    const short* arow = OutPb + (size_t)(nt * 32 + col) * 64 + l5 * 8;
    #pragma unroll
    for (int s = 0; s < 4; ++s) afr[s] = *(const bf16x8*)(arow + s * 16);

    bf16x8 bw[2][4];
    #pragma unroll
    for (int oh = 0; oh < 2; ++oh) {
        const float* wrow = Wo + (size_t)(oh * 32 + col) * 64 + l5 * 8;
        #pragma unroll
        for (int s = 0; s < 4; ++s) {
            float4 f0 = *(const float4*)(wrow + s * 16);
            float4 f1 = *(const float4*)(wrow + s * 16 + 4);
            union { bf16x8 v; short sh[8]; } u;
            u.sh[0] = f2bf(f0.x); u.sh[1] = f2bf(f0.y);
            u.sh[2] = f2bf(f0.z); u.sh[3] = f2bf(f0.w);
            u.sh[4] = f2bf(f1.x); u.sh[5] = f2bf(f1.y);
            u.sh[6] = f2bf(f1.z); u.sh[7] = f2bf(f1.w);
            bw[oh][s] = u.v;
        }
    }

    f32x16 d0 = zero16(), d1 = zero16();
    #pragma unroll
    for (int s = 0; s < 4; ++s) {
        d0 = MFMA32(afr[s], bw[0][s], d0);
        d1 = MFMA32(afr[s], bw[1][s], d1);
    }

    const int b  = br >> 2;
    const int gi = (br >> 1) & 1;
    const int gj = br & 1;

    #pragma unroll
    for (int oh = 0; oh < 2; ++oh) {
        const int oc = oh * 32 + col;
        const float bias = bo[oc];
        const f32x16& d = oh ? d1 : d0;
        #pragma unroll
        for (int q = 0; q < 4; ++q) {
            int nloc = 8 * q + 4 * l5;
            int nreg = nt * 32 + nloc;
            int wp   = nreg & 63;
            int ip   = nreg >> 6;
            float4 v = make_float4(d[4*q+0] + bias, d[4*q+1] + bias,
                                   d[4*q+2] + bias, d[4*q+3] + bias);
            float* op = out + ((size_t)(b * 64 + oc)) * 16384
                        + (size_t)(gi * 64 + ip) * 128 + gj * 64 + wp;
            *(float4*)op = v;
        }
    }
}

// -------------------------------------------------------------------- launch
extern "C" void kernel_launch(void* const* d_in, const int* in_sizes, int n_in,
                              void* d_out, int out_size, void* d_ws, size_t ws_size,
                              hipStream_t stream)
{
    const float* x  = (const float*)d_in[0];
    const float* Wq = (const float*)d_in[1];
    const float* bq = (const float*)d_in[2];
    const float* Wk = (const float*)d_in[3];
    const float* bk = (const float*)d_in[4];
    const float* Wa = (const float*)d_in[5];
    const float* ba = (const float*)d_in[6];
    const float* Wb = (const float*)d_in[7];
    const float* bb = (const float*)d_in[8];
    const float* Wo = (const float*)d_in[9];
    const float* bo = (const float*)d_in[10];
    char* ws   = (char*)d_ws;
    float* out = (float*)d_out;

    hipLaunchKernelGGL(k_conv_in,  dim3(512),  dim3(256), 0, stream,
                       x, Wq, bq, Wk, bk, Wa, ba, Wb, bb, ws);
    hipLaunchKernelGGL(k_stats,    dim3(512),  dim3(256), 0, stream, ws);
    hipLaunchKernelGGL(k_attn,     dim3(512),  dim3(256), 0, stream, ws);
    hipLaunchKernelGGL(k_conv_out, dim3(1024), dim3(64),  0, stream,
                       ws, Wo, bo, out);
}